// Round 1
// baseline (303.976 us; speedup 1.0000x reference)
//
#include <hip/hip_runtime.h>

typedef __bf16 bf16;
typedef __bf16 bf16x2 __attribute__((ext_vector_type(2)));
typedef __bf16 bf16x4 __attribute__((ext_vector_type(4)));
typedef __bf16 bf16x8 __attribute__((ext_vector_type(8)));
typedef float f32x4 __attribute__((ext_vector_type(4)));

typedef __attribute__((address_space(1))) const void g_void;
typedef __attribute__((address_space(3))) void l_void;

constexpr int Bsz = 4, S = 2048, H = 512, NH = 8, DH = 64;
constexpr int M = Bsz * S;   // 8192 rows
constexpr int K = H;         // 512 reduction dim
constexpr int WELEM = H * H; // 262144 elems per weight matrix
constexpr float LOG2E  = 1.44269504f;
constexpr float QSCALE = 0.125f * LOG2E;  // fold 1/sqrt(DH)*log2e into q

// ---------------------------------------------------------------------------
// Weight convert: fp32 -> bf16. grid=(256,4): y picks which weight.
// ---------------------------------------------------------------------------
__global__ __launch_bounds__(256) void convert_w(
    const float* __restrict__ w0, const float* __restrict__ w1,
    const float* __restrict__ w2, const float* __restrict__ w3,
    bf16* __restrict__ dst) {
    int y = blockIdx.y;
    const float* src = (y == 0) ? w0 : (y == 1) ? w1 : (y == 2) ? w2 : w3;
    bf16* d = dst + (size_t)y * WELEM;
    int i = (blockIdx.x * 256 + threadIdx.x) * 4;
    float4 v = *(const float4*)(src + i);
    bf16x4 o;
    o.x = (bf16)v.x; o.y = (bf16)v.y; o.z = (bf16)v.z; o.w = (bf16)v.w;
    *(bf16x4*)(d + i) = o;
}

// mask * log2e -> fp32 scratch (for exp2-based softmax)
__global__ __launch_bounds__(256) void scale_mask(
    const float* __restrict__ m, float* __restrict__ out) {
    int i = blockIdx.x * 256 + threadIdx.x;
    out[i] = m[i] * LOG2E;
}

// ---------------------------------------------------------------------------
// LN1: fp32 in -> bf16 out. One block per row, 256 threads x 2 elems.
// ---------------------------------------------------------------------------
__global__ __launch_bounds__(256) void ln_f32_bf16(
    const float* __restrict__ x, const float* __restrict__ g,
    const float* __restrict__ b, bf16* __restrict__ y) {
    int row = blockIdx.x;
    int t = threadIdx.x;
    float2 xv = *(const float2*)(x + (size_t)row * H + t * 2);
    float v0 = xv.x, v1 = xv.y;
    float s = v0 + v1, s2 = v0 * v0 + v1 * v1;
    for (int off = 1; off < 64; off <<= 1) {
        s  += __shfl_xor(s,  off, 64);
        s2 += __shfl_xor(s2, off, 64);
    }
    __shared__ float red[8];
    int wid = t >> 6;
    if ((t & 63) == 0) { red[wid * 2] = s; red[wid * 2 + 1] = s2; }
    __syncthreads();
    s  = red[0] + red[2] + red[4] + red[6];
    s2 = red[1] + red[3] + red[5] + red[7];
    float mu  = s * (1.0f / H);
    float var = s2 * (1.0f / H) - mu * mu;
    float inv = rsqrtf(var + 1e-12f);
    float2 gv = *(const float2*)(g + t * 2);
    float2 bv = *(const float2*)(b + t * 2);
    bf16x2 out;
    out.x = (bf16)((v0 - mu) * inv * gv.x + bv.x);
    out.y = (bf16)((v1 - mu) * inv * gv.y + bv.y);
    *(bf16x2*)(y + (size_t)row * H + t * 2) = out;
}

// LN2: bf16 in -> fp32 out.
__global__ __launch_bounds__(256) void ln_bf16_f32(
    const bf16* __restrict__ x, const float* __restrict__ g,
    const float* __restrict__ b, float* __restrict__ y) {
    int row = blockIdx.x;
    int t = threadIdx.x;
    bf16x2 xv = *(const bf16x2*)(x + (size_t)row * H + t * 2);
    float v0 = (float)xv.x, v1 = (float)xv.y;
    float s = v0 + v1, s2 = v0 * v0 + v1 * v1;
    for (int off = 1; off < 64; off <<= 1) {
        s  += __shfl_xor(s,  off, 64);
        s2 += __shfl_xor(s2, off, 64);
    }
    __shared__ float red[8];
    int wid = t >> 6;
    if ((t & 63) == 0) { red[wid * 2] = s; red[wid * 2 + 1] = s2; }
    __syncthreads();
    s  = red[0] + red[2] + red[4] + red[6];
    s2 = red[1] + red[3] + red[5] + red[7];
    float mu  = s * (1.0f / H);
    float var = s2 * (1.0f / H) - mu * mu;
    float inv = rsqrtf(var + 1e-12f);
    float2 gv = *(const float2*)(g + t * 2);
    float2 bv = *(const float2*)(b + t * 2);
    float2 out;
    out.x = (v0 - mu) * inv * gv.x + bv.x;
    out.y = (v1 - mu) * inv * gv.y + bv.y;
    *(float2*)(y + (size_t)row * H + t * 2) = out;
}

// ---------------------------------------------------------------------------
// m97-style GEMM mainloop: C[128x128] tile of A[M,K]@W[N,K]^T.
// 256 thr = 4 waves, each wave a 64x64 quadrant (4x4 MFMA 16x16x32).
// global_load_lds width-16 staging (2-barrier K-loop, BK=64), XOR-swizzled
// unpadded LDS (sel=(row&7)*8) -> <=2-way conflicts on b128 frag reads.
// ---------------------------------------------------------------------------
__device__ inline void gemm128_mainloop(const bf16* __restrict__ A,
                                        const bf16* __restrict__ W,
                                        int bm, int bn,
                                        bf16* As, bf16* Bs, f32x4 acc[4][4]) {
    int t = threadIdx.x;
    int lane = t & 63, wid = t >> 6;
    int quad = lane >> 4, n = lane & 15;
    int wm = wid & 1, wn = wid >> 1;
    int sw = (n & 7) * 8;                // frag-read xor (row&7)*8, row%8==n%8
    int srow = lane >> 3;                // staging: row within 8-row chunk
    int scol = (lane & 7) * 8;           // staging: col base (elems)
    for (int kt = 0; kt < K; kt += 64) {
        __syncthreads();                 // prior tile's readers done
        #pragma unroll
        for (int i = 0; i < 4; i++) {
            int chunk = wid * 4 + i;     // wave-uniform
            int row = chunk * 8 + srow;
            int csrc = scol ^ ((row & 7) * 8);
            __builtin_amdgcn_global_load_lds(
                (g_void*)&A[(size_t)(bm + row) * K + kt + csrc],
                (l_void*)&As[chunk * 512], 16, 0, 0);
            __builtin_amdgcn_global_load_lds(
                (g_void*)&W[(size_t)(bn + row) * K + kt + csrc],
                (l_void*)&Bs[chunk * 512], 16, 0, 0);
        }
        __syncthreads();                 // drains vmcnt(0) before compute
        #pragma unroll
        for (int half = 0; half < 2; half++) {
            bf16x8 af[4], bf[4];
            #pragma unroll
            for (int mi = 0; mi < 4; mi++) {
                int c = (half * 32 + quad * 8) ^ sw;
                af[mi] = *(const bf16x8*)&As[(wm * 64 + mi * 16 + n) * 64 + c];
                bf[mi] = *(const bf16x8*)&Bs[(wn * 64 + mi * 16 + n) * 64 + c];
            }
            #pragma unroll
            for (int mi = 0; mi < 4; mi++)
                #pragma unroll
                for (int ni = 0; ni < 4; ni++)
                    acc[mi][ni] = __builtin_amdgcn_mfma_f32_16x16x32_bf16(
                        af[mi], bf[ni], acc[mi][ni], 0, 0, 0);
        }
    }
}

// QKV projection. grid = (M/128, H/128, 3); z=0:q (pre-scaled by QSCALE),
// z=1:k (both [B,NH,S,DH]), z=2: v transposed [B,NH,DH,S].
__global__ __launch_bounds__(256) void gemm_qkv(
    const bf16* __restrict__ h, const bf16* __restrict__ wb,
    const float* __restrict__ bq, const float* __restrict__ bk,
    const float* __restrict__ bv,
    bf16* __restrict__ qd, bf16* __restrict__ kd, bf16* __restrict__ vtd) {
    __shared__ alignas(16) bf16 As[128 * 64];
    __shared__ alignas(16) bf16 Bs[128 * 64];
    int bm = blockIdx.x * 128, bn = blockIdx.y * 128, z = blockIdx.z;
    const bf16* W = wb + (size_t)z * WELEM;
    const float* bias = (z == 0) ? bq : (z == 1) ? bk : bv;
    f32x4 acc[4][4];
    for (int mi = 0; mi < 4; mi++)
        for (int ni = 0; ni < 4; ni++)
            for (int r = 0; r < 4; r++) acc[mi][ni][r] = 0.0f;
    gemm128_mainloop(h, W, bm, bn, As, Bs, acc);
    int lane = threadIdx.x & 63, wid = threadIdx.x >> 6;
    int quad = lane >> 4, n = lane & 15;
    int wm = wid & 1, wn = wid >> 1;
    for (int mi = 0; mi < 4; mi++)
        for (int ni = 0; ni < 4; ni++)
            for (int r = 0; r < 4; r++) {
                int i = bm + wm * 64 + mi * 16 + quad * 4 + r;
                int j = bn + wn * 64 + ni * 16 + n;
                float val = acc[mi][ni][r] + bias[j];
                if (z == 0) val *= QSCALE;
                int b = i >> 11, srow = i & (S - 1);
                int nh = j >> 6, d = j & (DH - 1);
                if (z < 2) {
                    bf16* dst = (z == 0) ? qd : kd;
                    dst[(((size_t)(b * NH + nh)) * S + srow) * DH + d] = (bf16)val;
                } else {
                    vtd[(((size_t)(b * NH + nh)) * DH + d) * S + srow] = (bf16)val;
                }
            }
}

// Output projection + bias + residual(h) -> tmp (bf16, row-major [M,H])
__global__ __launch_bounds__(256) void gemm_out(
    const bf16* __restrict__ ctx, const bf16* __restrict__ wo,
    const float* __restrict__ bo, const bf16* __restrict__ resid,
    bf16* __restrict__ dst) {
    __shared__ alignas(16) bf16 As[128 * 64];
    __shared__ alignas(16) bf16 Bs[128 * 64];
    int bm = blockIdx.x * 128, bn = blockIdx.y * 128;
    f32x4 acc[4][4];
    for (int mi = 0; mi < 4; mi++)
        for (int ni = 0; ni < 4; ni++)
            for (int r = 0; r < 4; r++) acc[mi][ni][r] = 0.0f;
    gemm128_mainloop(ctx, wo, bm, bn, As, Bs, acc);
    int lane = threadIdx.x & 63, wid = threadIdx.x >> 6;
    int quad = lane >> 4, n = lane & 15;
    int wm = wid & 1, wn = wid >> 1;
    for (int mi = 0; mi < 4; mi++)
        for (int ni = 0; ni < 4; ni++)
            for (int r = 0; r < 4; r++) {
                int i = bm + wm * 64 + mi * 16 + quad * 4 + r;
                int j = bn + wn * 64 + ni * 16 + n;
                float val = acc[mi][ni][r] + bo[j]
                          + (float)resid[(size_t)i * H + j];
                dst[(size_t)i * H + j] = (bf16)val;
            }
}

// ---------------------------------------------------------------------------
// Flash attention v6: v5 restructured from 128-row to 64-row Q tiles.
// Grid doubles to 1024 blocks (4 blocks/CU vs 2) to fix the latency-bound
// occupancy cap (OccupancyPercent was 19%, grid-limited at 2 blocks/CU).
// Each of the 4 waves owns 16 q-rows. LDS: Ks 18KB + Ps 17KB = 35.8KB
// -> 4 blocks/CU; VGPR budget (qf 8 + O 16 + vfr 64 + temps) fits 4 w/SIMD.
// ---------------------------------------------------------------------------
constexpr int LDK2 = 72;    // K tile row stride (64 + 8 pad)
constexpr int LDP  = 136;   // P row stride (128 + 8 pad)

#if __has_builtin(__builtin_amdgcn_exp2f)
#define EXP2(x) __builtin_amdgcn_exp2f(x)
#else
#define EXP2(x) exp2f(x)
#endif

__global__ __launch_bounds__(256, 4) void attn_kernel(
    const bf16* __restrict__ q, const bf16* __restrict__ k,
    const bf16* __restrict__ vt, const float* __restrict__ mask2,
    bf16* __restrict__ ctx) {
    int bh = blockIdx.y;                 // b*NH + nh
    int b = bh >> 3, nh = bh & 7;
    int t = threadIdx.x, wid = t >> 6, lane = t & 63;
    int quad = lane >> 4, n = lane & 15;
    int qbase = blockIdx.x * 64 + wid * 16;

    const bf16* Qp = q  + (size_t)bh * S * DH;
    const bf16* Kp = k  + (size_t)bh * S * DH;
    const bf16* Vt = vt + (size_t)bh * DH * S;
    const float* mrow = mask2 + (size_t)b * S;   // pre-scaled by log2e

    __shared__ alignas(16) bf16 Ks[128 * LDK2];   // [key][d]
    __shared__ alignas(16) bf16 Ps[4][16 * LDP];  // per-wave P^T [q][key]
    bf16* Pw = Ps[wid];

    bf16x8 qf[2];
    #pragma unroll
    for (int hh = 0; hh < 2; hh++)
        qf[hh] = *(const bf16x8*)
            &Qp[(size_t)(qbase + n) * DH + hh * 32 + quad * 8];

    f32x4 O[4];
    #pragma unroll
    for (int i = 0; i < 4; i++)
        for (int r = 0; r < 4; r++) O[i][r] = 0.0f;
    float l_run = 0.0f;

    for (int kb = 0; kb < S; kb += 128) {
        __syncthreads();
        #pragma unroll
        for (int i = 0; i < 4; i++) {    // stage K 128x64 (16 KB)
            int c = t + i * 256, row = c >> 3, part = c & 7;
            *(uint4*)&Ks[row * LDK2 + part * 8] =
                *(const uint4*)&Kp[(size_t)(kb + row) * DH + part * 8];
        }
        __syncthreads();

        bf16x8 vfr[4][4];                // V direct from global, issued early
        #pragma unroll
        for (int ks = 0; ks < 4; ks++)
            #pragma unroll
            for (int dt = 0; dt < 4; dt++)
                vfr[ks][dt] = *(const bf16x8*)
                    &Vt[(size_t)(dt * 16 + n) * S + kb + ks * 32 + quad * 8];

        #pragma unroll
        for (int kt = 0; kt < 8; kt++) {
            const bf16* kr = &Ks[(kt * 16 + n) * LDK2];
            bf16x8 ka = *(const bf16x8*)&kr[quad * 8];
            bf16x8 kc = *(const bf16x8*)&kr[32 + quad * 8];
            float4 mk = *(const float4*)&mrow[kb + kt * 16 + quad * 4];
            f32x4 s;
            for (int r = 0; r < 4; r++) s[r] = 0.0f;
            s = __builtin_amdgcn_mfma_f32_16x16x32_bf16(ka, qf[0], s, 0, 0, 0);
            s = __builtin_amdgcn_mfma_f32_16x16x32_bf16(kc, qf[1], s, 0, 0, 0);
            float p0 = EXP2(s[0] + mk.x);
            float p1 = EXP2(s[1] + mk.y);
            float p2 = EXP2(s[2] + mk.z);
            float p3 = EXP2(s[3] + mk.w);
            l_run += (p0 + p1) + (p2 + p3);
            bf16x4 w;
            w[0] = (bf16)p0; w[1] = (bf16)p1; w[2] = (bf16)p2; w[3] = (bf16)p3;
            *(bf16x4*)&Pw[n * LDP + kt * 16 + quad * 4] = w;
        }

        #pragma unroll
        for (int ks = 0; ks < 4; ks++) {
            bf16x8 pf = *(const bf16x8*)&Pw[n * LDP + ks * 32 + quad * 8];
            #pragma unroll
            for (int dt = 0; dt < 4; dt++)
                O[dt] = __builtin_amdgcn_mfma_f32_16x16x32_bf16(
                    vfr[ks][dt], pf, O[dt], 0, 0, 0);
        }
    }

    float l = l_run;
    l += __shfl_xor(l, 16, 64);
    l += __shfl_xor(l, 32, 64);
    float linv = 1.0f / l;
    int srow = qbase + n;
    #pragma unroll
    for (int dt = 0; dt < 4; dt++) {
        bf16x4 o4;
        for (int r = 0; r < 4; r++) o4[r] = (bf16)(O[dt][r] * linv);
        int col = nh * 64 + dt * 16 + quad * 4;
        *(bf16x4*)&ctx[((size_t)(b * S + srow)) * H + col] = o4;
    }
}

// ---------------------------------------------------------------------------
extern "C" void kernel_launch(void* const* d_in, const int* in_sizes, int n_in,
                              void* d_out, int out_size, void* d_ws, size_t ws_size,
                              hipStream_t stream) {
    const float* hidden = (const float*)d_in[0];
    const float* mask   = (const float*)d_in[1];
    const float* ln1_g  = (const float*)d_in[2];
    const float* ln1_b  = (const float*)d_in[3];
    const float* wq = (const float*)d_in[4],  *bq = (const float*)d_in[5];
    const float* wk = (const float*)d_in[6],  *bk = (const float*)d_in[7];
    const float* wv = (const float*)d_in[8],  *bv = (const float*)d_in[9];
    const float* wo = (const float*)d_in[10], *bo = (const float*)d_in[11];
    const float* ln2_g = (const float*)d_in[12];
    const float* ln2_b = (const float*)d_in[13];

    const size_t T = (size_t)M * H;     // 4M elems per activation tensor
    bf16* wb  = (bf16*)d_ws;            // 4 weights, bf16: 4*WELEM
    bf16* h   = wb  + (size_t)4 * WELEM;
    bf16* qd  = h   + T;
    bf16* kd  = qd  + T;
    bf16* vtd = kd  + T;
    bf16* ctx = vtd + T;
    float* mask2 = (float*)(ctx + T);   // B*S fp32, mask*log2e
    bf16* tmp = qd;                     // qd is dead after attn_kernel

    convert_w<<<dim3(WELEM / 1024, 4), 256, 0, stream>>>(wq, wk, wv, wo, wb);
    scale_mask<<<Bsz * S / 256, 256, 0, stream>>>(mask, mask2);
    ln_f32_bf16<<<M, 256, 0, stream>>>(hidden, ln1_g, ln1_b, h);
    gemm_qkv<<<dim3(M / 128, H / 128, 3), 256, 0, stream>>>(
        h, wb, bq, bk, bv, qd, kd, vtd);
    attn_kernel<<<dim3(S / 64, Bsz * NH), 256, 0, stream>>>(qd, kd, vtd, mask2, ctx);
    gemm_out<<<dim3(M / 128, H / 128), 256, 0, stream>>>(
        ctx, wb + (size_t)3 * WELEM, bo, h, tmp);
    ln_bf16_f32<<<M, 256, 0, stream>>>(tmp, ln2_g, ln2_b, (float*)d_out);
}

// Round 3
// 234.034 us; speedup vs baseline: 1.2989x; 1.2989x over previous
//
#include <hip/hip_runtime.h>

typedef __bf16 bf16;
typedef __bf16 bf16x2 __attribute__((ext_vector_type(2)));
typedef __bf16 bf16x4 __attribute__((ext_vector_type(4)));
typedef __bf16 bf16x8 __attribute__((ext_vector_type(8)));
typedef float f32x4 __attribute__((ext_vector_type(4)));

typedef __attribute__((address_space(1))) const void g_void;
typedef __attribute__((address_space(3))) void l_void;

constexpr int Bsz = 4, S = 2048, H = 512, NH = 8, DH = 64;
constexpr int M = Bsz * S;   // 8192 rows
constexpr int K = H;         // 512 reduction dim
constexpr int WELEM = H * H; // 262144 elems per weight matrix
constexpr float LOG2E  = 1.44269504f;
constexpr float QSCALE = 0.125f * LOG2E;  // fold 1/sqrt(DH)*log2e into q

// ---------------------------------------------------------------------------
// Weight convert: fp32 -> bf16. grid=(256,4): y picks which weight.
// ---------------------------------------------------------------------------
__global__ __launch_bounds__(256) void convert_w(
    const float* __restrict__ w0, const float* __restrict__ w1,
    const float* __restrict__ w2, const float* __restrict__ w3,
    bf16* __restrict__ dst) {
    int y = blockIdx.y;
    const float* src = (y == 0) ? w0 : (y == 1) ? w1 : (y == 2) ? w2 : w3;
    bf16* d = dst + (size_t)y * WELEM;
    int i = (blockIdx.x * 256 + threadIdx.x) * 4;
    float4 v = *(const float4*)(src + i);
    bf16x4 o;
    o.x = (bf16)v.x; o.y = (bf16)v.y; o.z = (bf16)v.z; o.w = (bf16)v.w;
    *(bf16x4*)(d + i) = o;
}

// mask * log2e -> fp32 scratch (for exp2-based softmax)
__global__ __launch_bounds__(256) void scale_mask(
    const float* __restrict__ m, float* __restrict__ out) {
    int i = blockIdx.x * 256 + threadIdx.x;
    out[i] = m[i] * LOG2E;
}

// ---------------------------------------------------------------------------
// LN1: fp32 in -> bf16 out. One block per row, 256 threads x 2 elems.
// ---------------------------------------------------------------------------
__global__ __launch_bounds__(256) void ln_f32_bf16(
    const float* __restrict__ x, const float* __restrict__ g,
    const float* __restrict__ b, bf16* __restrict__ y) {
    int row = blockIdx.x;
    int t = threadIdx.x;
    float2 xv = *(const float2*)(x + (size_t)row * H + t * 2);
    float v0 = xv.x, v1 = xv.y;
    float s = v0 + v1, s2 = v0 * v0 + v1 * v1;
    for (int off = 1; off < 64; off <<= 1) {
        s  += __shfl_xor(s,  off, 64);
        s2 += __shfl_xor(s2, off, 64);
    }
    __shared__ float red[8];
    int wid = t >> 6;
    if ((t & 63) == 0) { red[wid * 2] = s; red[wid * 2 + 1] = s2; }
    __syncthreads();
    s  = red[0] + red[2] + red[4] + red[6];
    s2 = red[1] + red[3] + red[5] + red[7];
    float mu  = s * (1.0f / H);
    float var = s2 * (1.0f / H) - mu * mu;
    float inv = rsqrtf(var + 1e-12f);
    float2 gv = *(const float2*)(g + t * 2);
    float2 bv = *(const float2*)(b + t * 2);
    bf16x2 out;
    out.x = (bf16)((v0 - mu) * inv * gv.x + bv.x);
    out.y = (bf16)((v1 - mu) * inv * gv.y + bv.y);
    *(bf16x2*)(y + (size_t)row * H + t * 2) = out;
}

// LN2: bf16 in -> fp32 out.
__global__ __launch_bounds__(256) void ln_bf16_f32(
    const bf16* __restrict__ x, const float* __restrict__ g,
    const float* __restrict__ b, float* __restrict__ y) {
    int row = blockIdx.x;
    int t = threadIdx.x;
    bf16x2 xv = *(const bf16x2*)(x + (size_t)row * H + t * 2);
    float v0 = (float)xv.x, v1 = (float)xv.y;
    float s = v0 + v1, s2 = v0 * v0 + v1 * v1;
    for (int off = 1; off < 64; off <<= 1) {
        s  += __shfl_xor(s,  off, 64);
        s2 += __shfl_xor(s2, off, 64);
    }
    __shared__ float red[8];
    int wid = t >> 6;
    if ((t & 63) == 0) { red[wid * 2] = s; red[wid * 2 + 1] = s2; }
    __syncthreads();
    s  = red[0] + red[2] + red[4] + red[6];
    s2 = red[1] + red[3] + red[5] + red[7];
    float mu  = s * (1.0f / H);
    float var = s2 * (1.0f / H) - mu * mu;
    float inv = rsqrtf(var + 1e-12f);
    float2 gv = *(const float2*)(g + t * 2);
    float2 bv = *(const float2*)(b + t * 2);
    float2 out;
    out.x = (v0 - mu) * inv * gv.x + bv.x;
    out.y = (v1 - mu) * inv * gv.y + bv.y;
    *(float2*)(y + (size_t)row * H + t * 2) = out;
}

// ---------------------------------------------------------------------------
// m97-style GEMM mainloop: C[128x128] tile of A[M,K]@W[N,K]^T.
// 256 thr = 4 waves, each wave a 64x64 quadrant (4x4 MFMA 16x16x32).
// global_load_lds width-16 staging (2-barrier K-loop, BK=64), XOR-swizzled
// unpadded LDS (sel=(row&7)*8) -> <=2-way conflicts on b128 frag reads.
// ---------------------------------------------------------------------------
__device__ inline void gemm128_mainloop(const bf16* __restrict__ A,
                                        const bf16* __restrict__ W,
                                        int bm, int bn,
                                        bf16* As, bf16* Bs, f32x4 acc[4][4]) {
    int t = threadIdx.x;
    int lane = t & 63, wid = t >> 6;
    int quad = lane >> 4, n = lane & 15;
    int wm = wid & 1, wn = wid >> 1;
    int sw = (n & 7) * 8;                // frag-read xor (row&7)*8, row%8==n%8
    int srow = lane >> 3;                // staging: row within 8-row chunk
    int scol = (lane & 7) * 8;           // staging: col base (elems)
    for (int kt = 0; kt < K; kt += 64) {
        __syncthreads();                 // prior tile's readers done
        #pragma unroll
        for (int i = 0; i < 4; i++) {
            int chunk = wid * 4 + i;     // wave-uniform
            int row = chunk * 8 + srow;
            int csrc = scol ^ ((row & 7) * 8);
            __builtin_amdgcn_global_load_lds(
                (g_void*)&A[(size_t)(bm + row) * K + kt + csrc],
                (l_void*)&As[chunk * 512], 16, 0, 0);
            __builtin_amdgcn_global_load_lds(
                (g_void*)&W[(size_t)(bn + row) * K + kt + csrc],
                (l_void*)&Bs[chunk * 512], 16, 0, 0);
        }
        __syncthreads();                 // drains vmcnt(0) before compute
        #pragma unroll
        for (int half = 0; half < 2; half++) {
            bf16x8 af[4], bf[4];
            #pragma unroll
            for (int mi = 0; mi < 4; mi++) {
                int c = (half * 32 + quad * 8) ^ sw;
                af[mi] = *(const bf16x8*)&As[(wm * 64 + mi * 16 + n) * 64 + c];
                bf[mi] = *(const bf16x8*)&Bs[(wn * 64 + mi * 16 + n) * 64 + c];
            }
            #pragma unroll
            for (int mi = 0; mi < 4; mi++)
                #pragma unroll
                for (int ni = 0; ni < 4; ni++)
                    acc[mi][ni] = __builtin_amdgcn_mfma_f32_16x16x32_bf16(
                        af[mi], bf[ni], acc[mi][ni], 0, 0, 0);
        }
    }
}

// QKV projection. grid = (M/128, H/128, 3); z=0:q (pre-scaled by QSCALE),
// z=1:k (both [B,NH,S,DH]), z=2: v transposed [B,NH,DH,S].
__global__ __launch_bounds__(256) void gemm_qkv(
    const bf16* __restrict__ h, const bf16* __restrict__ wb,
    const float* __restrict__ bq, const float* __restrict__ bk,
    const float* __restrict__ bv,
    bf16* __restrict__ qd, bf16* __restrict__ kd, bf16* __restrict__ vtd) {
    __shared__ alignas(16) bf16 As[128 * 64];
    __shared__ alignas(16) bf16 Bs[128 * 64];
    int bm = blockIdx.x * 128, bn = blockIdx.y * 128, z = blockIdx.z;
    const bf16* W = wb + (size_t)z * WELEM;
    const float* bias = (z == 0) ? bq : (z == 1) ? bk : bv;
    f32x4 acc[4][4];
    for (int mi = 0; mi < 4; mi++)
        for (int ni = 0; ni < 4; ni++)
            for (int r = 0; r < 4; r++) acc[mi][ni][r] = 0.0f;
    gemm128_mainloop(h, W, bm, bn, As, Bs, acc);
    int lane = threadIdx.x & 63, wid = threadIdx.x >> 6;
    int quad = lane >> 4, n = lane & 15;
    int wm = wid & 1, wn = wid >> 1;
    for (int mi = 0; mi < 4; mi++)
        for (int ni = 0; ni < 4; ni++)
            for (int r = 0; r < 4; r++) {
                int i = bm + wm * 64 + mi * 16 + quad * 4 + r;
                int j = bn + wn * 64 + ni * 16 + n;
                float val = acc[mi][ni][r] + bias[j];
                if (z == 0) val *= QSCALE;
                int b = i >> 11, srow = i & (S - 1);
                int nh = j >> 6, d = j & (DH - 1);
                if (z < 2) {
                    bf16* dst = (z == 0) ? qd : kd;
                    dst[(((size_t)(b * NH + nh)) * S + srow) * DH + d] = (bf16)val;
                } else {
                    vtd[(((size_t)(b * NH + nh)) * DH + d) * S + srow] = (bf16)val;
                }
            }
}

// Output projection + bias + residual(h) -> tmp (bf16, row-major [M,H])
__global__ __launch_bounds__(256) void gemm_out(
    const bf16* __restrict__ ctx, const bf16* __restrict__ wo,
    const float* __restrict__ bo, const bf16* __restrict__ resid,
    bf16* __restrict__ dst) {
    __shared__ alignas(16) bf16 As[128 * 64];
    __shared__ alignas(16) bf16 Bs[128 * 64];
    int bm = blockIdx.x * 128, bn = blockIdx.y * 128;
    f32x4 acc[4][4];
    for (int mi = 0; mi < 4; mi++)
        for (int ni = 0; ni < 4; ni++)
            for (int r = 0; r < 4; r++) acc[mi][ni][r] = 0.0f;
    gemm128_mainloop(ctx, wo, bm, bn, As, Bs, acc);
    int lane = threadIdx.x & 63, wid = threadIdx.x >> 6;
    int quad = lane >> 4, n = lane & 15;
    int wm = wid & 1, wn = wid >> 1;
    for (int mi = 0; mi < 4; mi++)
        for (int ni = 0; ni < 4; ni++)
            for (int r = 0; r < 4; r++) {
                int i = bm + wm * 64 + mi * 16 + quad * 4 + r;
                int j = bn + wn * 64 + ni * 16 + n;
                float val = acc[mi][ni][r] + bo[j]
                          + (float)resid[(size_t)i * H + j];
                dst[(size_t)i * H + j] = (bf16)val;
            }
}

// ---------------------------------------------------------------------------
// Flash attention v7: v5 geometry (128-row Q tiles, proven 92us) + pipelined
// K staging. K tile double-buffered in LDS, staged via global_load_lds
// (width 16) issued at the TOP of each iteration into the other buffer;
// the single end-of-iteration __syncthreads (which drains vmcnt anyway) is
// exactly when the data is needed -> staging latency hides under QK+PV.
// One barrier per iteration instead of two. Ks is unpadded + XOR-swizzled
// (col ^ (row&7)*8, both sides) as required by global_load_lds' linear
// dest; frag reads land 2-way bank conflicts (free per m136).
// LDS: 2*16KB Ks + 34.8KB Ps = 66.8KB -> 2 blocks/CU.
// ---------------------------------------------------------------------------
constexpr int LDP  = 136;   // P row stride (128 + 8 pad)

#if __has_builtin(__builtin_amdgcn_exp2f)
#define EXP2(x) __builtin_amdgcn_exp2f(x)
#else
#define EXP2(x) exp2f(x)
#endif

__global__ __launch_bounds__(256, 2) void attn_kernel(
    const bf16* __restrict__ q, const bf16* __restrict__ k,
    const bf16* __restrict__ vt, const float* __restrict__ mask2,
    bf16* __restrict__ ctx) {
    int bh = blockIdx.y;                 // b*NH + nh
    int b = bh >> 3, nh = bh & 7;
    int t = threadIdx.x, wid = t >> 6, lane = t & 63;
    int quad = lane >> 4, n = lane & 15;
    int qbase = blockIdx.x * 128 + wid * 32;

    const bf16* Qp = q  + (size_t)bh * S * DH;
    const bf16* Kp = k  + (size_t)bh * S * DH;
    const bf16* Vt = vt + (size_t)bh * DH * S;
    const float* mrow = mask2 + (size_t)b * S;   // pre-scaled by log2e

    __shared__ alignas(16) bf16 Ks[2][128 * 64];  // dbuf [key][d], swizzled
    __shared__ alignas(16) bf16 Ps[4][32 * LDP];  // per-wave P^T [q][key]
    bf16* Pw = Ps[wid];

    int srow8 = lane >> 3;               // staging: row within 8-row chunk
    int scol  = (lane & 7) * 8;          // staging: col base (elems)
    int sw    = (n & 7) * 8;             // frag-read xor

    bf16x8 qf[2][2];
    #pragma unroll
    for (int qt = 0; qt < 2; qt++)
        #pragma unroll
        for (int hh = 0; hh < 2; hh++)
            qf[qt][hh] = *(const bf16x8*)
                &Qp[(size_t)(qbase + qt * 16 + n) * DH + hh * 32 + quad * 8];

    f32x4 O[2][4];
    #pragma unroll
    for (int qt = 0; qt < 2; qt++)
        for (int i = 0; i < 4; i++)
            for (int r = 0; r < 4; r++) O[qt][i][r] = 0.0f;
    float l_run[2] = {0.0f, 0.0f};

    // prologue: stage tile 0 into buf 0
    #pragma unroll
    for (int i = 0; i < 4; i++) {
        int chunk = wid * 4 + i;
        int row = chunk * 8 + srow8;
        int csrc = scol ^ ((row & 7) * 8);
        __builtin_amdgcn_global_load_lds(
            (g_void*)&Kp[(size_t)row * DH + csrc],
            (l_void*)&Ks[0][chunk * 512], 16, 0, 0);
    }
    __syncthreads();

    constexpr int NT = S / 128;          // 16
    for (int it = 0; it < NT; ++it) {
        int kb = it * 128;
        const bf16* Kc = Ks[it & 1];

        if (it + 1 < NT) {               // async DMA next K tile into other buf
            bf16* dst = Ks[(it + 1) & 1];
            #pragma unroll
            for (int i = 0; i < 4; i++) {
                int chunk = wid * 4 + i;
                int row = chunk * 8 + srow8;
                int csrc = scol ^ ((row & 7) * 8);
                __builtin_amdgcn_global_load_lds(
                    (g_void*)&Kp[(size_t)(kb + 128 + row) * DH + csrc],
                    (l_void*)&dst[chunk * 512], 16, 0, 0);
            }
        }

        bf16x8 vfr[4][4];                // V direct from global, issued early
        #pragma unroll
        for (int ks = 0; ks < 4; ks++)
            #pragma unroll
            for (int dt = 0; dt < 4; dt++)
                vfr[ks][dt] = *(const bf16x8*)
                    &Vt[(size_t)(dt * 16 + n) * S + kb + ks * 32 + quad * 8];

        #pragma unroll
        for (int kt = 0; kt < 8; kt++) {
            const bf16* kr = &Kc[(kt * 16 + n) * 64];
            bf16x8 ka = *(const bf16x8*)&kr[(quad * 8) ^ sw];
            bf16x8 kc = *(const bf16x8*)&kr[(32 + quad * 8) ^ sw];
            float4 mk = *(const float4*)&mrow[kb + kt * 16 + quad * 4];
            #pragma unroll
            for (int qt = 0; qt < 2; qt++) {
                f32x4 s;
                for (int r = 0; r < 4; r++) s[r] = 0.0f;
                s = __builtin_amdgcn_mfma_f32_16x16x32_bf16(ka, qf[qt][0], s, 0, 0, 0);
                s = __builtin_amdgcn_mfma_f32_16x16x32_bf16(kc, qf[qt][1], s, 0, 0, 0);
                float p0 = EXP2(s[0] + mk.x);
                float p1 = EXP2(s[1] + mk.y);
                float p2 = EXP2(s[2] + mk.z);
                float p3 = EXP2(s[3] + mk.w);
                l_run[qt] += (p0 + p1) + (p2 + p3);
                bf16x4 w;
                w[0] = (bf16)p0; w[1] = (bf16)p1; w[2] = (bf16)p2; w[3] = (bf16)p3;
                *(bf16x4*)&Pw[(qt * 16 + n) * LDP + kt * 16 + quad * 4] = w;
            }
        }

        __builtin_amdgcn_s_setprio(1);
        #pragma unroll
        for (int ks = 0; ks < 4; ks++)
            #pragma unroll
            for (int qt = 0; qt < 2; qt++) {
                bf16x8 pf = *(const bf16x8*)
                    &Pw[(qt * 16 + n) * LDP + ks * 32 + quad * 8];
                #pragma unroll
                for (int dt = 0; dt < 4; dt++)
                    O[qt][dt] = __builtin_amdgcn_mfma_f32_16x16x32_bf16(
                        vfr[ks][dt], pf, O[qt][dt], 0, 0, 0);
            }
        __builtin_amdgcn_s_setprio(0);

        __syncthreads();                 // drains vmcnt: next K tile landed;
                                         // all waves done reading Kc
    }

    #pragma unroll
    for (int qt = 0; qt < 2; qt++) {
        float l = l_run[qt];
        l += __shfl_xor(l, 16, 64);
        l += __shfl_xor(l, 32, 64);
        float linv = 1.0f / l;
        int srow = qbase + qt * 16 + n;
        #pragma unroll
        for (int dt = 0; dt < 4; dt++) {
            bf16x4 o4;
            for (int r = 0; r < 4; r++) o4[r] = (bf16)(O[qt][dt][r] * linv);
            int col = nh * 64 + dt * 16 + quad * 4;
            *(bf16x4*)&ctx[((size_t)(b * S + srow)) * H + col] = o4;
        }
    }
}

// ---------------------------------------------------------------------------
extern "C" void kernel_launch(void* const* d_in, const int* in_sizes, int n_in,
                              void* d_out, int out_size, void* d_ws, size_t ws_size,
                              hipStream_t stream) {
    const float* hidden = (const float*)d_in[0];
    const float* mask   = (const float*)d_in[1];
    const float* ln1_g  = (const float*)d_in[2];
    const float* ln1_b  = (const float*)d_in[3];
    const float* wq = (const float*)d_in[4],  *bq = (const float*)d_in[5];
    const float* wk = (const float*)d_in[6],  *bk = (const float*)d_in[7];
    const float* wv = (const float*)d_in[8],  *bv = (const float*)d_in[9];
    const float* wo = (const float*)d_in[10], *bo = (const float*)d_in[11];
    const float* ln2_g = (const float*)d_in[12];
    const float* ln2_b = (const float*)d_in[13];

    const size_t T = (size_t)M * H;     // 4M elems per activation tensor
    bf16* wb  = (bf16*)d_ws;            // 4 weights, bf16: 4*WELEM
    bf16* h   = wb  + (size_t)4 * WELEM;
    bf16* qd  = h   + T;
    bf16* kd  = qd  + T;
    bf16* vtd = kd  + T;
    bf16* ctx = vtd + T;
    float* mask2 = (float*)(ctx + T);   // B*S fp32, mask*log2e
    bf16* tmp = qd;                     // qd is dead after attn_kernel

    convert_w<<<dim3(WELEM / 1024, 4), 256, 0, stream>>>(wq, wk, wv, wo, wb);
    scale_mask<<<Bsz * S / 256, 256, 0, stream>>>(mask, mask2);
    ln_f32_bf16<<<M, 256, 0, stream>>>(hidden, ln1_g, ln1_b, h);
    gemm_qkv<<<dim3(M / 128, H / 128, 3), 256, 0, stream>>>(
        h, wb, bq, bk, bv, qd, kd, vtd);
    attn_kernel<<<dim3(S / 128, Bsz * NH), 256, 0, stream>>>(qd, kd, vtd, mask2, ctx);
    gemm_out<<<dim3(M / 128, H / 128), 256, 0, stream>>>(
        ctx, wb + (size_t)3 * WELEM, bo, h, tmp);
    ln_bf16_f32<<<M, 256, 0, stream>>>(tmp, ln2_g, ln2_b, (float*)d_out);
}

// Round 4
// 205.553 us; speedup vs baseline: 1.4788x; 1.1386x over previous
//
#include <hip/hip_runtime.h>

typedef __bf16 bf16;
typedef __bf16 bf16x2 __attribute__((ext_vector_type(2)));
typedef __bf16 bf16x4 __attribute__((ext_vector_type(4)));
typedef __bf16 bf16x8 __attribute__((ext_vector_type(8)));
typedef float f32x4 __attribute__((ext_vector_type(4)));

typedef __attribute__((address_space(1))) const void g_void;
typedef __attribute__((address_space(3))) void l_void;

constexpr int Bsz = 4, S = 2048, H = 512, NH = 8, DH = 64;
constexpr int M = Bsz * S;   // 8192 rows
constexpr int K = H;         // 512 reduction dim
constexpr int WELEM = H * H; // 262144 elems per weight matrix
constexpr float LOG2E  = 1.44269504f;
constexpr float QSCALE = 0.125f * LOG2E;  // fold 1/sqrt(DH)*log2e into q

// ---------------------------------------------------------------------------
// Weight convert: fp32 -> bf16. grid=(256,4): y picks which weight.
// ---------------------------------------------------------------------------
__global__ __launch_bounds__(256) void convert_w(
    const float* __restrict__ w0, const float* __restrict__ w1,
    const float* __restrict__ w2, const float* __restrict__ w3,
    bf16* __restrict__ dst) {
    int y = blockIdx.y;
    const float* src = (y == 0) ? w0 : (y == 1) ? w1 : (y == 2) ? w2 : w3;
    bf16* d = dst + (size_t)y * WELEM;
    int i = (blockIdx.x * 256 + threadIdx.x) * 4;
    float4 v = *(const float4*)(src + i);
    bf16x4 o;
    o.x = (bf16)v.x; o.y = (bf16)v.y; o.z = (bf16)v.z; o.w = (bf16)v.w;
    *(bf16x4*)(d + i) = o;
}

// mask * log2e -> fp32 scratch (for exp2-based softmax)
__global__ __launch_bounds__(256) void scale_mask(
    const float* __restrict__ m, float* __restrict__ out) {
    int i = blockIdx.x * 256 + threadIdx.x;
    out[i] = m[i] * LOG2E;
}

// ---------------------------------------------------------------------------
// LN1: fp32 in -> bf16 out. One block per row, 256 threads x 2 elems.
// ---------------------------------------------------------------------------
__global__ __launch_bounds__(256) void ln_f32_bf16(
    const float* __restrict__ x, const float* __restrict__ g,
    const float* __restrict__ b, bf16* __restrict__ y) {
    int row = blockIdx.x;
    int t = threadIdx.x;
    float2 xv = *(const float2*)(x + (size_t)row * H + t * 2);
    float v0 = xv.x, v1 = xv.y;
    float s = v0 + v1, s2 = v0 * v0 + v1 * v1;
    for (int off = 1; off < 64; off <<= 1) {
        s  += __shfl_xor(s,  off, 64);
        s2 += __shfl_xor(s2, off, 64);
    }
    __shared__ float red[8];
    int wid = t >> 6;
    if ((t & 63) == 0) { red[wid * 2] = s; red[wid * 2 + 1] = s2; }
    __syncthreads();
    s  = red[0] + red[2] + red[4] + red[6];
    s2 = red[1] + red[3] + red[5] + red[7];
    float mu  = s * (1.0f / H);
    float var = s2 * (1.0f / H) - mu * mu;
    float inv = rsqrtf(var + 1e-12f);
    float2 gv = *(const float2*)(g + t * 2);
    float2 bv = *(const float2*)(b + t * 2);
    bf16x2 out;
    out.x = (bf16)((v0 - mu) * inv * gv.x + bv.x);
    out.y = (bf16)((v1 - mu) * inv * gv.y + bv.y);
    *(bf16x2*)(y + (size_t)row * H + t * 2) = out;
}

// LN2: bf16 in -> fp32 out.
__global__ __launch_bounds__(256) void ln_bf16_f32(
    const bf16* __restrict__ x, const float* __restrict__ g,
    const float* __restrict__ b, float* __restrict__ y) {
    int row = blockIdx.x;
    int t = threadIdx.x;
    bf16x2 xv = *(const bf16x2*)(x + (size_t)row * H + t * 2);
    float v0 = (float)xv.x, v1 = (float)xv.y;
    float s = v0 + v1, s2 = v0 * v0 + v1 * v1;
    for (int off = 1; off < 64; off <<= 1) {
        s  += __shfl_xor(s,  off, 64);
        s2 += __shfl_xor(s2, off, 64);
    }
    __shared__ float red[8];
    int wid = t >> 6;
    if ((t & 63) == 0) { red[wid * 2] = s; red[wid * 2 + 1] = s2; }
    __syncthreads();
    s  = red[0] + red[2] + red[4] + red[6];
    s2 = red[1] + red[3] + red[5] + red[7];
    float mu  = s * (1.0f / H);
    float var = s2 * (1.0f / H) - mu * mu;
    float inv = rsqrtf(var + 1e-12f);
    float2 gv = *(const float2*)(g + t * 2);
    float2 bv = *(const float2*)(b + t * 2);
    float2 out;
    out.x = (v0 - mu) * inv * gv.x + bv.x;
    out.y = (v1 - mu) * inv * gv.y + bv.y;
    *(float2*)(y + (size_t)row * H + t * 2) = out;
}

// ---------------------------------------------------------------------------
// m97-style GEMM mainloop: C[128x128] tile of A[M,K]@W[N,K]^T.
// 256 thr = 4 waves, each wave a 64x64 quadrant (4x4 MFMA 16x16x32).
// global_load_lds width-16 staging (2-barrier K-loop, BK=64), XOR-swizzled
// unpadded LDS (sel=(row&7)*8) -> <=2-way conflicts on b128 frag reads.
// ---------------------------------------------------------------------------
__device__ inline void gemm128_mainloop(const bf16* __restrict__ A,
                                        const bf16* __restrict__ W,
                                        int bm, int bn,
                                        bf16* As, bf16* Bs, f32x4 acc[4][4]) {
    int t = threadIdx.x;
    int lane = t & 63, wid = t >> 6;
    int quad = lane >> 4, n = lane & 15;
    int wm = wid & 1, wn = wid >> 1;
    int sw = (n & 7) * 8;                // frag-read xor (row&7)*8, row%8==n%8
    int srow = lane >> 3;                // staging: row within 8-row chunk
    int scol = (lane & 7) * 8;           // staging: col base (elems)
    for (int kt = 0; kt < K; kt += 64) {
        __syncthreads();                 // prior tile's readers done
        #pragma unroll
        for (int i = 0; i < 4; i++) {
            int chunk = wid * 4 + i;     // wave-uniform
            int row = chunk * 8 + srow;
            int csrc = scol ^ ((row & 7) * 8);
            __builtin_amdgcn_global_load_lds(
                (g_void*)&A[(size_t)(bm + row) * K + kt + csrc],
                (l_void*)&As[chunk * 512], 16, 0, 0);
            __builtin_amdgcn_global_load_lds(
                (g_void*)&W[(size_t)(bn + row) * K + kt + csrc],
                (l_void*)&Bs[chunk * 512], 16, 0, 0);
        }
        __syncthreads();                 // drains vmcnt(0) before compute
        #pragma unroll
        for (int half = 0; half < 2; half++) {
            bf16x8 af[4], bf[4];
            #pragma unroll
            for (int mi = 0; mi < 4; mi++) {
                int c = (half * 32 + quad * 8) ^ sw;
                af[mi] = *(const bf16x8*)&As[(wm * 64 + mi * 16 + n) * 64 + c];
                bf[mi] = *(const bf16x8*)&Bs[(wn * 64 + mi * 16 + n) * 64 + c];
            }
            #pragma unroll
            for (int mi = 0; mi < 4; mi++)
                #pragma unroll
                for (int ni = 0; ni < 4; ni++)
                    acc[mi][ni] = __builtin_amdgcn_mfma_f32_16x16x32_bf16(
                        af[mi], bf[ni], acc[mi][ni], 0, 0, 0);
        }
    }
}

// QKV projection. grid = (M/128, H/128, 3); z=0:q (pre-scaled by QSCALE),
// z=1:k (both [B,NH,S,DH]), z=2: v transposed [B,NH,DH,S].
__global__ __launch_bounds__(256) void gemm_qkv(
    const bf16* __restrict__ h, const bf16* __restrict__ wb,
    const float* __restrict__ bq, const float* __restrict__ bk,
    const float* __restrict__ bv,
    bf16* __restrict__ qd, bf16* __restrict__ kd, bf16* __restrict__ vtd) {
    __shared__ alignas(16) bf16 As[128 * 64];
    __shared__ alignas(16) bf16 Bs[128 * 64];
    int bm = blockIdx.x * 128, bn = blockIdx.y * 128, z = blockIdx.z;
    const bf16* W = wb + (size_t)z * WELEM;
    const float* bias = (z == 0) ? bq : (z == 1) ? bk : bv;
    f32x4 acc[4][4];
    for (int mi = 0; mi < 4; mi++)
        for (int ni = 0; ni < 4; ni++)
            for (int r = 0; r < 4; r++) acc[mi][ni][r] = 0.0f;
    gemm128_mainloop(h, W, bm, bn, As, Bs, acc);
    int lane = threadIdx.x & 63, wid = threadIdx.x >> 6;
    int quad = lane >> 4, n = lane & 15;
    int wm = wid & 1, wn = wid >> 1;
    for (int mi = 0; mi < 4; mi++)
        for (int ni = 0; ni < 4; ni++)
            for (int r = 0; r < 4; r++) {
                int i = bm + wm * 64 + mi * 16 + quad * 4 + r;
                int j = bn + wn * 64 + ni * 16 + n;
                float val = acc[mi][ni][r] + bias[j];
                if (z == 0) val *= QSCALE;
                int b = i >> 11, srow = i & (S - 1);
                int nh = j >> 6, d = j & (DH - 1);
                if (z < 2) {
                    bf16* dst = (z == 0) ? qd : kd;
                    dst[(((size_t)(b * NH + nh)) * S + srow) * DH + d] = (bf16)val;
                } else {
                    vtd[(((size_t)(b * NH + nh)) * DH + d) * S + srow] = (bf16)val;
                }
            }
}

// Output projection + bias + residual(h) -> tmp (bf16, row-major [M,H])
__global__ __launch_bounds__(256) void gemm_out(
    const bf16* __restrict__ ctx, const bf16* __restrict__ wo,
    const float* __restrict__ bo, const bf16* __restrict__ resid,
    bf16* __restrict__ dst) {
    __shared__ alignas(16) bf16 As[128 * 64];
    __shared__ alignas(16) bf16 Bs[128 * 64];
    int bm = blockIdx.x * 128, bn = blockIdx.y * 128;
    f32x4 acc[4][4];
    for (int mi = 0; mi < 4; mi++)
        for (int ni = 0; ni < 4; ni++)
            for (int r = 0; r < 4; r++) acc[mi][ni][r] = 0.0f;
    gemm128_mainloop(ctx, wo, bm, bn, As, Bs, acc);
    int lane = threadIdx.x & 63, wid = threadIdx.x >> 6;
    int quad = lane >> 4, n = lane & 15;
    int wm = wid & 1, wn = wid >> 1;
    for (int mi = 0; mi < 4; mi++)
        for (int ni = 0; ni < 4; ni++)
            for (int r = 0; r < 4; r++) {
                int i = bm + wm * 64 + mi * 16 + quad * 4 + r;
                int j = bn + wn * 64 + ni * 16 + n;
                float val = acc[mi][ni][r] + bo[j]
                          + (float)resid[(size_t)i * H + j];
                dst[(size_t)i * H + j] = (bf16)val;
            }
}

// ---------------------------------------------------------------------------
// Flash attention v8: occupancy restructure. 512 thr = 8 waves per block,
// each wave owns a 16-row Q tile (block still covers 128 Q rows; grid
// unchanged 16x32). Per-SIMD work per iteration is conserved vs v7
// (4 waves x 32 MFMA = 2 x 64), but resident waves/CU double: 8 -> 16
// (4/SIMD) to hide the MFMA->exp2->LDS->MFMA dependency chains that
// dominated at 2 waves/SIMD (MfmaUtil 15%, VALUBusy 22%, 60%+ stall).
// V is now staged to LDS (global_load_lds, XOR-swizzled both sides) so
// the narrower per-wave Q tile does not double L2 V traffic.
// LDS: Ks 16KB + Vs 16KB + Ps 8x4.25KB = 66.6KB -> 2 blocks/CU.
// ---------------------------------------------------------------------------
constexpr int LDP  = 136;   // P row stride (128 + 8 pad)

#if __has_builtin(__builtin_amdgcn_exp2f)
#define EXP2(x) __builtin_amdgcn_exp2f(x)
#else
#define EXP2(x) exp2f(x)
#endif

__global__ __launch_bounds__(512, 4) void attn_kernel(
    const bf16* __restrict__ q, const bf16* __restrict__ k,
    const bf16* __restrict__ vt, const float* __restrict__ mask2,
    bf16* __restrict__ ctx) {
    int bh = blockIdx.y;                 // b*NH + nh
    int b = bh >> 3, nh = bh & 7;
    int t = threadIdx.x, wid = t >> 6, lane = t & 63;
    int quad = lane >> 4, n = lane & 15;
    int qbase = blockIdx.x * 128 + wid * 16;   // 16 q-rows per wave

    const bf16* Qp = q  + (size_t)bh * S * DH;
    const bf16* Kp = k  + (size_t)bh * S * DH;
    const bf16* Vt = vt + (size_t)bh * DH * S;
    const float* mrow = mask2 + (size_t)b * S;   // pre-scaled by log2e

    __shared__ alignas(16) bf16 Ks[128 * 64];    // [key][d], swizzled
    __shared__ alignas(16) bf16 Vs[64 * 128];    // [d][key], swizzled
    __shared__ alignas(16) bf16 Ps[8][16 * LDP]; // per-wave P^T [q][key]
    bf16* Pw = Ps[wid];

    int sw = (n & 7) * 8;                // frag-read xor

    bf16x8 qf[2];
    #pragma unroll
    for (int hh = 0; hh < 2; hh++)
        qf[hh] = *(const bf16x8*)
            &Qp[(size_t)(qbase + n) * DH + hh * 32 + quad * 8];

    f32x4 O[4];
    #pragma unroll
    for (int i = 0; i < 4; i++)
        for (int r = 0; r < 4; r++) O[i][r] = 0.0f;
    float l_run = 0.0f;

    for (int kb = 0; kb < S; kb += 128) {
        __syncthreads();                 // prior tile's readers done
        #pragma unroll
        for (int i = 0; i < 2; i++) {    // stage K 128x64 + V^T 64x128
            int c = t + i * 512;
            {   // K: row=key (64 elems/row), unit=16B
                int row = c >> 3, part = c & 7;
                int csrc = (part * 8) ^ ((row & 7) * 8);
                __builtin_amdgcn_global_load_lds(
                    (g_void*)&Kp[(size_t)(kb + row) * DH + csrc],
                    (l_void*)&Ks[c * 8], 16, 0, 0);
            }
            {   // V^T: row=d (128 elems/row), unit=16B
                int row = c >> 4, part = c & 15;
                int csrc = (part * 8) ^ ((row & 7) * 8);
                __builtin_amdgcn_global_load_lds(
                    (g_void*)&Vt[(size_t)row * S + kb + csrc],
                    (l_void*)&Vs[c * 8], 16, 0, 0);
            }
        }
        __syncthreads();                 // drains vmcnt(0): tiles landed

        #pragma unroll
        for (int kt = 0; kt < 8; kt++) {
            const bf16* kr = &Ks[(kt * 16 + n) * 64];
            bf16x8 ka = *(const bf16x8*)&kr[(quad * 8) ^ sw];
            bf16x8 kc = *(const bf16x8*)&kr[(32 + quad * 8) ^ sw];
            float4 mk = *(const float4*)&mrow[kb + kt * 16 + quad * 4];
            f32x4 s;
            for (int r = 0; r < 4; r++) s[r] = 0.0f;
            s = __builtin_amdgcn_mfma_f32_16x16x32_bf16(ka, qf[0], s, 0, 0, 0);
            s = __builtin_amdgcn_mfma_f32_16x16x32_bf16(kc, qf[1], s, 0, 0, 0);
            float p0 = EXP2(s[0] + mk.x);
            float p1 = EXP2(s[1] + mk.y);
            float p2 = EXP2(s[2] + mk.z);
            float p3 = EXP2(s[3] + mk.w);
            l_run += (p0 + p1) + (p2 + p3);
            bf16x4 w;
            w[0] = (bf16)p0; w[1] = (bf16)p1; w[2] = (bf16)p2; w[3] = (bf16)p3;
            *(bf16x4*)&Pw[n * LDP + kt * 16 + quad * 4] = w;
        }

        __builtin_amdgcn_s_setprio(1);
        #pragma unroll
        for (int ks = 0; ks < 4; ks++) {
            bf16x8 pf = *(const bf16x8*)&Pw[n * LDP + ks * 32 + quad * 8];
            #pragma unroll
            for (int dt = 0; dt < 4; dt++) {
                bf16x8 vf = *(const bf16x8*)
                    &Vs[(dt * 16 + n) * 128 + ((ks * 32 + quad * 8) ^ sw)];
                O[dt] = __builtin_amdgcn_mfma_f32_16x16x32_bf16(
                    vf, pf, O[dt], 0, 0, 0);
            }
        }
        __builtin_amdgcn_s_setprio(0);
    }

    float l = l_run;
    l += __shfl_xor(l, 16, 64);
    l += __shfl_xor(l, 32, 64);
    float linv = 1.0f / l;
    int srow = qbase + n;
    #pragma unroll
    for (int dt = 0; dt < 4; dt++) {
        bf16x4 o4;
        for (int r = 0; r < 4; r++) o4[r] = (bf16)(O[dt][r] * linv);
        int col = nh * 64 + dt * 16 + quad * 4;
        *(bf16x4*)&ctx[((size_t)(b * S + srow)) * H + col] = o4;
    }
}

// ---------------------------------------------------------------------------
extern "C" void kernel_launch(void* const* d_in, const int* in_sizes, int n_in,
                              void* d_out, int out_size, void* d_ws, size_t ws_size,
                              hipStream_t stream) {
    const float* hidden = (const float*)d_in[0];
    const float* mask   = (const float*)d_in[1];
    const float* ln1_g  = (const float*)d_in[2];
    const float* ln1_b  = (const float*)d_in[3];
    const float* wq = (const float*)d_in[4],  *bq = (const float*)d_in[5];
    const float* wk = (const float*)d_in[6],  *bk = (const float*)d_in[7];
    const float* wv = (const float*)d_in[8],  *bv = (const float*)d_in[9];
    const float* wo = (const float*)d_in[10], *bo = (const float*)d_in[11];
    const float* ln2_g = (const float*)d_in[12];
    const float* ln2_b = (const float*)d_in[13];

    const size_t T = (size_t)M * H;     // 4M elems per activation tensor
    bf16* wb  = (bf16*)d_ws;            // 4 weights, bf16: 4*WELEM
    bf16* h   = wb  + (size_t)4 * WELEM;
    bf16* qd  = h   + T;
    bf16* kd  = qd  + T;
    bf16* vtd = kd  + T;
    bf16* ctx = vtd + T;
    float* mask2 = (float*)(ctx + T);   // B*S fp32, mask*log2e
    bf16* tmp = qd;                     // qd is dead after attn_kernel

    convert_w<<<dim3(WELEM / 1024, 4), 256, 0, stream>>>(wq, wk, wv, wo, wb);
    scale_mask<<<Bsz * S / 256, 256, 0, stream>>>(mask, mask2);
    ln_f32_bf16<<<M, 256, 0, stream>>>(hidden, ln1_g, ln1_b, h);
    gemm_qkv<<<dim3(M / 128, H / 128, 3), 256, 0, stream>>>(
        h, wb, bq, bk, bv, qd, kd, vtd);
    attn_kernel<<<dim3(S / 128, Bsz * NH), 512, 0, stream>>>(qd, kd, vtd, mask2, ctx);
    gemm_out<<<dim3(M / 128, H / 128), 256, 0, stream>>>(
        ctx, wb + (size_t)3 * WELEM, bo, h, tmp);
    ln_bf16_f32<<<M, 256, 0, stream>>>(tmp, ln2_g, ln2_b, (float*)d_out);
}

// Round 5
// 202.081 us; speedup vs baseline: 1.5042x; 1.0172x over previous
//
#include <hip/hip_runtime.h>

typedef __bf16 bf16;
typedef __bf16 bf16x2 __attribute__((ext_vector_type(2)));
typedef __bf16 bf16x4 __attribute__((ext_vector_type(4)));
typedef __bf16 bf16x8 __attribute__((ext_vector_type(8)));
typedef float f32x4 __attribute__((ext_vector_type(4)));

typedef __attribute__((address_space(1))) const void g_void;
typedef __attribute__((address_space(3))) void l_void;

constexpr int Bsz = 4, S = 2048, H = 512, NH = 8, DH = 64;
constexpr int M = Bsz * S;   // 8192 rows
constexpr int K = H;         // 512 reduction dim
constexpr int WELEM = H * H; // 262144 elems per weight matrix
constexpr float LOG2E  = 1.44269504f;
constexpr float QSCALE = 0.125f * LOG2E;  // fold 1/sqrt(DH)*log2e into q

// ---------------------------------------------------------------------------
// Weight convert: fp32 -> bf16. grid=(256,4): y picks which weight.
// ---------------------------------------------------------------------------
__global__ __launch_bounds__(256) void convert_w(
    const float* __restrict__ w0, const float* __restrict__ w1,
    const float* __restrict__ w2, const float* __restrict__ w3,
    bf16* __restrict__ dst) {
    int y = blockIdx.y;
    const float* src = (y == 0) ? w0 : (y == 1) ? w1 : (y == 2) ? w2 : w3;
    bf16* d = dst + (size_t)y * WELEM;
    int i = (blockIdx.x * 256 + threadIdx.x) * 4;
    float4 v = *(const float4*)(src + i);
    bf16x4 o;
    o.x = (bf16)v.x; o.y = (bf16)v.y; o.z = (bf16)v.z; o.w = (bf16)v.w;
    *(bf16x4*)(d + i) = o;
}

// mask * log2e -> fp32 scratch (for exp2-based softmax)
__global__ __launch_bounds__(256) void scale_mask(
    const float* __restrict__ m, float* __restrict__ out) {
    int i = blockIdx.x * 256 + threadIdx.x;
    out[i] = m[i] * LOG2E;
}

// ---------------------------------------------------------------------------
// LN1: fp32 in -> bf16 out. One block per row, 256 threads x 2 elems.
// ---------------------------------------------------------------------------
__global__ __launch_bounds__(256) void ln_f32_bf16(
    const float* __restrict__ x, const float* __restrict__ g,
    const float* __restrict__ b, bf16* __restrict__ y) {
    int row = blockIdx.x;
    int t = threadIdx.x;
    float2 xv = *(const float2*)(x + (size_t)row * H + t * 2);
    float v0 = xv.x, v1 = xv.y;
    float s = v0 + v1, s2 = v0 * v0 + v1 * v1;
    for (int off = 1; off < 64; off <<= 1) {
        s  += __shfl_xor(s,  off, 64);
        s2 += __shfl_xor(s2, off, 64);
    }
    __shared__ float red[8];
    int wid = t >> 6;
    if ((t & 63) == 0) { red[wid * 2] = s; red[wid * 2 + 1] = s2; }
    __syncthreads();
    s  = red[0] + red[2] + red[4] + red[6];
    s2 = red[1] + red[3] + red[5] + red[7];
    float mu  = s * (1.0f / H);
    float var = s2 * (1.0f / H) - mu * mu;
    float inv = rsqrtf(var + 1e-12f);
    float2 gv = *(const float2*)(g + t * 2);
    float2 bv = *(const float2*)(b + t * 2);
    bf16x2 out;
    out.x = (bf16)((v0 - mu) * inv * gv.x + bv.x);
    out.y = (bf16)((v1 - mu) * inv * gv.y + bv.y);
    *(bf16x2*)(y + (size_t)row * H + t * 2) = out;
}

// LN2: bf16 in -> fp32 out.
__global__ __launch_bounds__(256) void ln_bf16_f32(
    const bf16* __restrict__ x, const float* __restrict__ g,
    const float* __restrict__ b, float* __restrict__ y) {
    int row = blockIdx.x;
    int t = threadIdx.x;
    bf16x2 xv = *(const bf16x2*)(x + (size_t)row * H + t * 2);
    float v0 = (float)xv.x, v1 = (float)xv.y;
    float s = v0 + v1, s2 = v0 * v0 + v1 * v1;
    for (int off = 1; off < 64; off <<= 1) {
        s  += __shfl_xor(s,  off, 64);
        s2 += __shfl_xor(s2, off, 64);
    }
    __shared__ float red[8];
    int wid = t >> 6;
    if ((t & 63) == 0) { red[wid * 2] = s; red[wid * 2 + 1] = s2; }
    __syncthreads();
    s  = red[0] + red[2] + red[4] + red[6];
    s2 = red[1] + red[3] + red[5] + red[7];
    float mu  = s * (1.0f / H);
    float var = s2 * (1.0f / H) - mu * mu;
    float inv = rsqrtf(var + 1e-12f);
    float2 gv = *(const float2*)(g + t * 2);
    float2 bv = *(const float2*)(b + t * 2);
    float2 out;
    out.x = (v0 - mu) * inv * gv.x + bv.x;
    out.y = (v1 - mu) * inv * gv.y + bv.y;
    *(float2*)(y + (size_t)row * H + t * 2) = out;
}

// ---------------------------------------------------------------------------
// m97-style GEMM mainloop: C[128x128] tile of A[M,K]@W[N,K]^T.
// 256 thr = 4 waves, each wave a 64x64 quadrant (4x4 MFMA 16x16x32).
// global_load_lds width-16 staging (2-barrier K-loop, BK=64), XOR-swizzled
// unpadded LDS (sel=(row&7)*8) -> <=2-way conflicts on b128 frag reads.
// ---------------------------------------------------------------------------
__device__ inline void gemm128_mainloop(const bf16* __restrict__ A,
                                        const bf16* __restrict__ W,
                                        int bm, int bn,
                                        bf16* As, bf16* Bs, f32x4 acc[4][4]) {
    int t = threadIdx.x;
    int lane = t & 63, wid = t >> 6;
    int quad = lane >> 4, n = lane & 15;
    int wm = wid & 1, wn = wid >> 1;
    int sw = (n & 7) * 8;                // frag-read xor (row&7)*8, row%8==n%8
    int srow = lane >> 3;                // staging: row within 8-row chunk
    int scol = (lane & 7) * 8;           // staging: col base (elems)
    for (int kt = 0; kt < K; kt += 64) {
        __syncthreads();                 // prior tile's readers done
        #pragma unroll
        for (int i = 0; i < 4; i++) {
            int chunk = wid * 4 + i;     // wave-uniform
            int row = chunk * 8 + srow;
            int csrc = scol ^ ((row & 7) * 8);
            __builtin_amdgcn_global_load_lds(
                (g_void*)&A[(size_t)(bm + row) * K + kt + csrc],
                (l_void*)&As[chunk * 512], 16, 0, 0);
            __builtin_amdgcn_global_load_lds(
                (g_void*)&W[(size_t)(bn + row) * K + kt + csrc],
                (l_void*)&Bs[chunk * 512], 16, 0, 0);
        }
        __syncthreads();                 // drains vmcnt(0) before compute
        #pragma unroll
        for (int half = 0; half < 2; half++) {
            bf16x8 af[4], bf[4];
            #pragma unroll
            for (int mi = 0; mi < 4; mi++) {
                int c = (half * 32 + quad * 8) ^ sw;
                af[mi] = *(const bf16x8*)&As[(wm * 64 + mi * 16 + n) * 64 + c];
                bf[mi] = *(const bf16x8*)&Bs[(wn * 64 + mi * 16 + n) * 64 + c];
            }
            #pragma unroll
            for (int mi = 0; mi < 4; mi++)
                #pragma unroll
                for (int ni = 0; ni < 4; ni++)
                    acc[mi][ni] = __builtin_amdgcn_mfma_f32_16x16x32_bf16(
                        af[mi], bf[ni], acc[mi][ni], 0, 0, 0);
        }
    }
}

// QKV projection. grid = (M/128, H/128, 3); z=0:q (pre-scaled by QSCALE),
// z=1:k (both [B,NH,S,DH]), z=2: v transposed [B,NH,DH,S].
__global__ __launch_bounds__(256) void gemm_qkv(
    const bf16* __restrict__ h, const bf16* __restrict__ wb,
    const float* __restrict__ bq, const float* __restrict__ bk,
    const float* __restrict__ bv,
    bf16* __restrict__ qd, bf16* __restrict__ kd, bf16* __restrict__ vtd) {
    __shared__ alignas(16) bf16 As[128 * 64];
    __shared__ alignas(16) bf16 Bs[128 * 64];
    int bm = blockIdx.x * 128, bn = blockIdx.y * 128, z = blockIdx.z;
    const bf16* W = wb + (size_t)z * WELEM;
    const float* bias = (z == 0) ? bq : (z == 1) ? bk : bv;
    f32x4 acc[4][4];
    for (int mi = 0; mi < 4; mi++)
        for (int ni = 0; ni < 4; ni++)
            for (int r = 0; r < 4; r++) acc[mi][ni][r] = 0.0f;
    gemm128_mainloop(h, W, bm, bn, As, Bs, acc);
    int lane = threadIdx.x & 63, wid = threadIdx.x >> 6;
    int quad = lane >> 4, n = lane & 15;
    int wm = wid & 1, wn = wid >> 1;
    for (int mi = 0; mi < 4; mi++)
        for (int ni = 0; ni < 4; ni++)
            for (int r = 0; r < 4; r++) {
                int i = bm + wm * 64 + mi * 16 + quad * 4 + r;
                int j = bn + wn * 64 + ni * 16 + n;
                float val = acc[mi][ni][r] + bias[j];
                if (z == 0) val *= QSCALE;
                int b = i >> 11, srow = i & (S - 1);
                int nh = j >> 6, d = j & (DH - 1);
                if (z < 2) {
                    bf16* dst = (z == 0) ? qd : kd;
                    dst[(((size_t)(b * NH + nh)) * S + srow) * DH + d] = (bf16)val;
                } else {
                    vtd[(((size_t)(b * NH + nh)) * DH + d) * S + srow] = (bf16)val;
                }
            }
}

// Output projection + bias + residual(h) -> tmp (bf16, row-major [M,H])
__global__ __launch_bounds__(256) void gemm_out(
    const bf16* __restrict__ ctx, const bf16* __restrict__ wo,
    const float* __restrict__ bo, const bf16* __restrict__ resid,
    bf16* __restrict__ dst) {
    __shared__ alignas(16) bf16 As[128 * 64];
    __shared__ alignas(16) bf16 Bs[128 * 64];
    int bm = blockIdx.x * 128, bn = blockIdx.y * 128;
    f32x4 acc[4][4];
    for (int mi = 0; mi < 4; mi++)
        for (int ni = 0; ni < 4; ni++)
            for (int r = 0; r < 4; r++) acc[mi][ni][r] = 0.0f;
    gemm128_mainloop(ctx, wo, bm, bn, As, Bs, acc);
    int lane = threadIdx.x & 63, wid = threadIdx.x >> 6;
    int quad = lane >> 4, n = lane & 15;
    int wm = wid & 1, wn = wid >> 1;
    for (int mi = 0; mi < 4; mi++)
        for (int ni = 0; ni < 4; ni++)
            for (int r = 0; r < 4; r++) {
                int i = bm + wm * 64 + mi * 16 + quad * 4 + r;
                int j = bn + wn * 64 + ni * 16 + n;
                float val = acc[mi][ni][r] + bo[j]
                          + (float)resid[(size_t)i * H + j];
                dst[(size_t)i * H + j] = (bf16)val;
            }
}

// ---------------------------------------------------------------------------
// Flash attention v9: key-split waves. 512 thr = 8 waves = 4 q-groups x
// 2 key-halves; each wave computes 32 q-rows x 64 keys per KV tile.
// Restores v7's per-wave LDS reuse (32 q-rows per K/V byte) at v8's
// occupancy (16 waves/CU): per-wave LDS frag reads drop 36 -> 20 b128
// per tile-iter (K 8, V 8, P 4), attacking the measured LDS-throughput
// bound (v8: ~430cy LDS vs 154cy MFMA per wave-iter, MfmaUtil 22%).
// O,l are pure sums over keys (no running max) so key-half partials
// combine once in the epilogue via LDS (fp32, stride-68 padded).
// LDS: Ks 16KB + Vs 16KB + Ps 8x4.5KB = 68KB -> 2 blocks/CU.
// ---------------------------------------------------------------------------
constexpr int LDP9 = 72;    // P row stride (64 + 8 pad)

#if __has_builtin(__builtin_amdgcn_exp2f)
#define EXP2(x) __builtin_amdgcn_exp2f(x)
#else
#define EXP2(x) exp2f(x)
#endif

__global__ __launch_bounds__(512, 4) void attn_kernel(
    const bf16* __restrict__ q, const bf16* __restrict__ k,
    const bf16* __restrict__ vt, const float* __restrict__ mask2,
    bf16* __restrict__ ctx) {
    int bh = blockIdx.y;                 // b*NH + nh
    int b = bh >> 3, nh = bh & 7;
    int t = threadIdx.x, wid = t >> 6, lane = t & 63;
    int quad = lane >> 4, n = lane & 15;
    int qg = wid >> 1, kh = wid & 1;     // q-group, key-half
    int qbase = blockIdx.x * 128 + qg * 32;
    int kO = kh * 64;                    // this wave's key offset in tile

    const bf16* Qp = q  + (size_t)bh * S * DH;
    const bf16* Kp = k  + (size_t)bh * S * DH;
    const bf16* Vt = vt + (size_t)bh * DH * S;
    const float* mrow = mask2 + (size_t)b * S;   // pre-scaled by log2e

    __shared__ alignas(16) bf16 smem[34816];     // 68KB
    bf16* Ks = smem;                     // [128 keys][64 d], swizzled
    bf16* Vs = smem + 8192;              // [64 d][128 keys], swizzled
    bf16* Pw = smem + 16384 + wid * (32 * LDP9); // per-wave P^T [q][key]

    int sw = (n & 7) * 8;                // frag-read xor

    bf16x8 qf[2][2];
    #pragma unroll
    for (int qt = 0; qt < 2; qt++)
        #pragma unroll
        for (int hh = 0; hh < 2; hh++)
            qf[qt][hh] = *(const bf16x8*)
                &Qp[(size_t)(qbase + qt * 16 + n) * DH + hh * 32 + quad * 8];

    f32x4 O[2][4];
    #pragma unroll
    for (int qt = 0; qt < 2; qt++)
        for (int i = 0; i < 4; i++)
            for (int r = 0; r < 4; r++) O[qt][i][r] = 0.0f;
    float l_run[2] = {0.0f, 0.0f};

    for (int kb = 0; kb < S; kb += 128) {
        __syncthreads();                 // prior tile's readers done
        #pragma unroll
        for (int i = 0; i < 2; i++) {    // stage K 128x64 + V^T 64x128
            int c = t + i * 512;
            {   // K: row=key (64 elems/row), unit=16B
                int row = c >> 3, part = c & 7;
                int csrc = (part * 8) ^ ((row & 7) * 8);
                __builtin_amdgcn_global_load_lds(
                    (g_void*)&Kp[(size_t)(kb + row) * DH + csrc],
                    (l_void*)&Ks[c * 8], 16, 0, 0);
            }
            {   // V^T: row=d (128 elems/row), unit=16B
                int row = c >> 4, part = c & 15;
                int csrc = (part * 8) ^ ((row & 7) * 8);
                __builtin_amdgcn_global_load_lds(
                    (g_void*)&Vt[(size_t)row * S + kb + csrc],
                    (l_void*)&Vs[c * 8], 16, 0, 0);
            }
        }
        __syncthreads();                 // drains vmcnt(0): tiles landed

        #pragma unroll
        for (int kt = 0; kt < 4; kt++) { // this wave's 64-key half
            const bf16* kr = &Ks[(kO + kt * 16 + n) * 64];
            bf16x8 ka = *(const bf16x8*)&kr[(quad * 8) ^ sw];
            bf16x8 kc = *(const bf16x8*)&kr[(32 + quad * 8) ^ sw];
            float4 mk = *(const float4*)&mrow[kb + kO + kt * 16 + quad * 4];
            #pragma unroll
            for (int qt = 0; qt < 2; qt++) {
                f32x4 s;
                for (int r = 0; r < 4; r++) s[r] = 0.0f;
                s = __builtin_amdgcn_mfma_f32_16x16x32_bf16(ka, qf[qt][0], s, 0, 0, 0);
                s = __builtin_amdgcn_mfma_f32_16x16x32_bf16(kc, qf[qt][1], s, 0, 0, 0);
                float p0 = EXP2(s[0] + mk.x);
                float p1 = EXP2(s[1] + mk.y);
                float p2 = EXP2(s[2] + mk.z);
                float p3 = EXP2(s[3] + mk.w);
                l_run[qt] += (p0 + p1) + (p2 + p3);
                bf16x4 w;
                w[0] = (bf16)p0; w[1] = (bf16)p1; w[2] = (bf16)p2; w[3] = (bf16)p3;
                *(bf16x4*)&Pw[(qt * 16 + n) * LDP9 + kt * 16 + quad * 4] = w;
            }
        }

        __builtin_amdgcn_s_setprio(1);
        #pragma unroll
        for (int ks = 0; ks < 2; ks++)
            #pragma unroll
            for (int qt = 0; qt < 2; qt++) {
                bf16x8 pf = *(const bf16x8*)
                    &Pw[(qt * 16 + n) * LDP9 + ks * 32 + quad * 8];
                #pragma unroll
                for (int dt = 0; dt < 4; dt++) {
                    bf16x8 vf = *(const bf16x8*)
                        &Vs[(dt * 16 + n) * 128 + ((kO + ks * 32 + quad * 8) ^ sw)];
                    O[qt][dt] = __builtin_amdgcn_mfma_f32_16x16x32_bf16(
                        vf, pf, O[qt][dt], 0, 0, 0);
                }
            }
        __builtin_amdgcn_s_setprio(0);
    }

    // --- combine key-half partials (O,l are pure sums) -------------------
    float* Ob = (float*)smem;            // [4 qg][32 q][68] fp32 (2-way banks)
    float* Lb = Ob + 4 * 32 * 68;        // [4 qg][2 qt][64 lanes]
    __syncthreads();                     // all compute done; smem reusable
    if (kh) {
        #pragma unroll
        for (int qt = 0; qt < 2; qt++) {
            #pragma unroll
            for (int dt = 0; dt < 4; dt++)
                *(f32x4*)&Ob[(qg * 32 + qt * 16 + n) * 68 + dt * 16 + quad * 4]
                    = O[qt][dt];
            Lb[(qg * 2 + qt) * 64 + lane] = l_run[qt];
        }
    }
    __syncthreads();
    if (!kh) {
        #pragma unroll
        for (int qt = 0; qt < 2; qt++) {
            float l = l_run[qt] + Lb[(qg * 2 + qt) * 64 + lane];
            l += __shfl_xor(l, 16, 64);
            l += __shfl_xor(l, 32, 64);
            float linv = 1.0f / l;
            int srow = qbase + qt * 16 + n;
            #pragma unroll
            for (int dt = 0; dt < 4; dt++) {
                f32x4 po = *(const f32x4*)
                    &Ob[(qg * 32 + qt * 16 + n) * 68 + dt * 16 + quad * 4];
                bf16x4 o4;
                for (int r = 0; r < 4; r++)
                    o4[r] = (bf16)((O[qt][dt][r] + po[r]) * linv);
                int col = nh * 64 + dt * 16 + quad * 4;
                *(bf16x4*)&ctx[((size_t)(b * S + srow)) * H + col] = o4;
            }
        }
    }
}

// ---------------------------------------------------------------------------
extern "C" void kernel_launch(void* const* d_in, const int* in_sizes, int n_in,
                              void* d_out, int out_size, void* d_ws, size_t ws_size,
                              hipStream_t stream) {
    const float* hidden = (const float*)d_in[0];
    const float* mask   = (const float*)d_in[1];
    const float* ln1_g  = (const float*)d_in[2];
    const float* ln1_b  = (const float*)d_in[3];
    const float* wq = (const float*)d_in[4],  *bq = (const float*)d_in[5];
    const float* wk = (const float*)d_in[6],  *bk = (const float*)d_in[7];
    const float* wv = (const float*)d_in[8],  *bv = (const float*)d_in[9];
    const float* wo = (const float*)d_in[10], *bo = (const float*)d_in[11];
    const float* ln2_g = (const float*)d_in[12];
    const float* ln2_b = (const float*)d_in[13];

    const size_t T = (size_t)M * H;     // 4M elems per activation tensor
    bf16* wb  = (bf16*)d_ws;            // 4 weights, bf16: 4*WELEM
    bf16* h   = wb  + (size_t)4 * WELEM;
    bf16* qd  = h   + T;
    bf16* kd  = qd  + T;
    bf16* vtd = kd  + T;
    bf16* ctx = vtd + T;
    float* mask2 = (float*)(ctx + T);   // B*S fp32, mask*log2e
    bf16* tmp = qd;                     // qd is dead after attn_kernel

    convert_w<<<dim3(WELEM / 1024, 4), 256, 0, stream>>>(wq, wk, wv, wo, wb);
    scale_mask<<<Bsz * S / 256, 256, 0, stream>>>(mask, mask2);
    ln_f32_bf16<<<M, 256, 0, stream>>>(hidden, ln1_g, ln1_b, h);
    gemm_qkv<<<dim3(M / 128, H / 128, 3), 256, 0, stream>>>(
        h, wb, bq, bk, bv, qd, kd, vtd);
    attn_kernel<<<dim3(S / 128, Bsz * NH), 512, 0, stream>>>(qd, kd, vtd, mask2, ctx);
    gemm_out<<<dim3(M / 128, H / 128), 256, 0, stream>>>(
        ctx, wb + (size_t)3 * WELEM, bo, h, tmp);
    ln_bf16_f32<<<M, 256, 0, stream>>>(tmp, ln2_g, ln2_b, (float*)d_out);
}

// Round 6
// 192.950 us; speedup vs baseline: 1.5754x; 1.0473x over previous
//
#include <hip/hip_runtime.h>

typedef __bf16 bf16;
typedef __bf16 bf16x2 __attribute__((ext_vector_type(2)));
typedef __bf16 bf16x4 __attribute__((ext_vector_type(4)));
typedef __bf16 bf16x8 __attribute__((ext_vector_type(8)));
typedef float f32x4 __attribute__((ext_vector_type(4)));

typedef __attribute__((address_space(1))) const void g_void;
typedef __attribute__((address_space(3))) void l_void;

constexpr int Bsz = 4, S = 2048, H = 512, NH = 8, DH = 64;
constexpr int M = Bsz * S;   // 8192 rows
constexpr int K = H;         // 512 reduction dim
constexpr int WELEM = H * H; // 262144 elems per weight matrix
constexpr float LOG2E  = 1.44269504f;
constexpr float QSCALE = 0.125f * LOG2E;  // fold 1/sqrt(DH)*log2e into q

// ---------------------------------------------------------------------------
// prep: fused convert_w (4 weights fp32->bf16) + scale_mask + ln1.
// grid.x = M (ln1) + 1024 (convert) + 32 (mask). Branch at block granularity
// (no intra-block divergence). Saves 2 kernel launches (~10us each gap).
// ---------------------------------------------------------------------------
__global__ __launch_bounds__(256) void prep(
    const float* __restrict__ hidden, const float* __restrict__ ln1_g,
    const float* __restrict__ ln1_b,
    const float* __restrict__ w0, const float* __restrict__ w1,
    const float* __restrict__ w2, const float* __restrict__ w3,
    const float* __restrict__ mask,
    bf16* __restrict__ h, bf16* __restrict__ wb, float* __restrict__ mask2) {
    int bx = blockIdx.x;
    int t = threadIdx.x;
    if (bx < M) {                        // ---- ln1: fp32 -> bf16, row = bx
        int row = bx;
        float2 xv = *(const float2*)(hidden + (size_t)row * H + t * 2);
        float v0 = xv.x, v1 = xv.y;
        float s = v0 + v1, s2 = v0 * v0 + v1 * v1;
        for (int off = 1; off < 64; off <<= 1) {
            s  += __shfl_xor(s,  off, 64);
            s2 += __shfl_xor(s2, off, 64);
        }
        __shared__ float red[8];
        int wid = t >> 6;
        if ((t & 63) == 0) { red[wid * 2] = s; red[wid * 2 + 1] = s2; }
        __syncthreads();
        s  = red[0] + red[2] + red[4] + red[6];
        s2 = red[1] + red[3] + red[5] + red[7];
        float mu  = s * (1.0f / H);
        float var = s2 * (1.0f / H) - mu * mu;
        float inv = rsqrtf(var + 1e-12f);
        float2 gv = *(const float2*)(ln1_g + t * 2);
        float2 bv = *(const float2*)(ln1_b + t * 2);
        bf16x2 out;
        out.x = (bf16)((v0 - mu) * inv * gv.x + bv.x);
        out.y = (bf16)((v1 - mu) * inv * gv.y + bv.y);
        *(bf16x2*)(h + (size_t)row * H + t * 2) = out;
    } else if (bx < M + 1024) {          // ---- convert_w
        int idx = bx - M;
        int y = idx >> 8, xx = idx & 255;
        const float* src = (y == 0) ? w0 : (y == 1) ? w1 : (y == 2) ? w2 : w3;
        bf16* d = wb + (size_t)y * WELEM;
        int i = (xx * 256 + t) * 4;
        float4 v = *(const float4*)(src + i);
        bf16x4 o;
        o.x = (bf16)v.x; o.y = (bf16)v.y; o.z = (bf16)v.z; o.w = (bf16)v.w;
        *(bf16x4*)(d + i) = o;
    } else {                             // ---- scale_mask
        int i = (bx - M - 1024) * 256 + t;
        mask2[i] = mask[i] * LOG2E;
    }
}

// LN2: bf16 in -> fp32 out.
__global__ __launch_bounds__(256) void ln_bf16_f32(
    const bf16* __restrict__ x, const float* __restrict__ g,
    const float* __restrict__ b, float* __restrict__ y) {
    int row = blockIdx.x;
    int t = threadIdx.x;
    bf16x2 xv = *(const bf16x2*)(x + (size_t)row * H + t * 2);
    float v0 = (float)xv.x, v1 = (float)xv.y;
    float s = v0 + v1, s2 = v0 * v0 + v1 * v1;
    for (int off = 1; off < 64; off <<= 1) {
        s  += __shfl_xor(s,  off, 64);
        s2 += __shfl_xor(s2, off, 64);
    }
    __shared__ float red[8];
    int wid = t >> 6;
    if ((t & 63) == 0) { red[wid * 2] = s; red[wid * 2 + 1] = s2; }
    __syncthreads();
    s  = red[0] + red[2] + red[4] + red[6];
    s2 = red[1] + red[3] + red[5] + red[7];
    float mu  = s * (1.0f / H);
    float var = s2 * (1.0f / H) - mu * mu;
    float inv = rsqrtf(var + 1e-12f);
    float2 gv = *(const float2*)(g + t * 2);
    float2 bv = *(const float2*)(b + t * 2);
    float2 out;
    out.x = (v0 - mu) * inv * gv.x + bv.x;
    out.y = (v1 - mu) * inv * gv.y + bv.y;
    *(float2*)(y + (size_t)row * H + t * 2) = out;
}

// ---------------------------------------------------------------------------
// m97-style GEMM mainloop: C[128x128] tile of A[M,K]@W[N,K]^T.
// 256 thr = 4 waves, each wave a 64x64 quadrant (4x4 MFMA 16x16x32).
// global_load_lds width-16 staging (2-barrier K-loop, BK=64), XOR-swizzled
// unpadded LDS (sel=(row&7)*8) -> <=2-way conflicts on b128 frag reads.
// ---------------------------------------------------------------------------
__device__ inline void gemm128_mainloop(const bf16* __restrict__ A,
                                        const bf16* __restrict__ W,
                                        int bm, int bn,
                                        bf16* As, bf16* Bs, f32x4 acc[4][4]) {
    int t = threadIdx.x;
    int lane = t & 63, wid = t >> 6;
    int quad = lane >> 4, n = lane & 15;
    int wm = wid & 1, wn = wid >> 1;
    int sw = (n & 7) * 8;                // frag-read xor (row&7)*8, row%8==n%8
    int srow = lane >> 3;                // staging: row within 8-row chunk
    int scol = (lane & 7) * 8;           // staging: col base (elems)
    for (int kt = 0; kt < K; kt += 64) {
        __syncthreads();                 // prior tile's readers done
        #pragma unroll
        for (int i = 0; i < 4; i++) {
            int chunk = wid * 4 + i;     // wave-uniform
            int row = chunk * 8 + srow;
            int csrc = scol ^ ((row & 7) * 8);
            __builtin_amdgcn_global_load_lds(
                (g_void*)&A[(size_t)(bm + row) * K + kt + csrc],
                (l_void*)&As[chunk * 512], 16, 0, 0);
            __builtin_amdgcn_global_load_lds(
                (g_void*)&W[(size_t)(bn + row) * K + kt + csrc],
                (l_void*)&Bs[chunk * 512], 16, 0, 0);
        }
        __syncthreads();                 // drains vmcnt(0) before compute
        #pragma unroll
        for (int half = 0; half < 2; half++) {
            bf16x8 af[4], bf[4];
            #pragma unroll
            for (int mi = 0; mi < 4; mi++) {
                int c = (half * 32 + quad * 8) ^ sw;
                af[mi] = *(const bf16x8*)&As[(wm * 64 + mi * 16 + n) * 64 + c];
                bf[mi] = *(const bf16x8*)&Bs[(wn * 64 + mi * 16 + n) * 64 + c];
            }
            #pragma unroll
            for (int mi = 0; mi < 4; mi++)
                #pragma unroll
                for (int ni = 0; ni < 4; ni++)
                    acc[mi][ni] = __builtin_amdgcn_mfma_f32_16x16x32_bf16(
                        af[mi], bf[ni], acc[mi][ni], 0, 0, 0);
        }
    }
}

// QKV projection. grid = (M/128, H/128, 3); z=0:q (pre-scaled by QSCALE),
// z=1:k (both [B,NH,S,DH]), z=2: v transposed [B,NH,DH,S].
// z=2 epilogue routes through an LDS transpose: the direct store pattern
// (2B per lane at 4KB stride, consecutive lanes on different d-rows) shreds
// into ~16 L2 transactions per store inst (4.2M insts). Transposed path:
// T[j][i] in LDS (pad 136, <=2-way banks), then 16 lanes stream one d-row
// -> fully coalesced 16B stores, 8x fewer insts, ~1 txn each.
// ---------------------------------------------------------------------------
__global__ __launch_bounds__(256) void gemm_qkv(
    const bf16* __restrict__ h, const bf16* __restrict__ wb,
    const float* __restrict__ bq, const float* __restrict__ bk,
    const float* __restrict__ bv,
    bf16* __restrict__ qd, bf16* __restrict__ kd, bf16* __restrict__ vtd) {
    __shared__ alignas(16) bf16 smem[17408];   // 34.8KB: As+Bs | T[128][136]
    bf16* As = smem;
    bf16* Bs = smem + 8192;
    int bm = blockIdx.x * 128, bn = blockIdx.y * 128, z = blockIdx.z;
    const bf16* W = wb + (size_t)z * WELEM;
    const float* bias = (z == 0) ? bq : (z == 1) ? bk : bv;
    f32x4 acc[4][4];
    for (int mi = 0; mi < 4; mi++)
        for (int ni = 0; ni < 4; ni++)
            for (int r = 0; r < 4; r++) acc[mi][ni][r] = 0.0f;
    gemm128_mainloop(h, W, bm, bn, As, Bs, acc);
    int t = threadIdx.x;
    int lane = t & 63, wid = t >> 6;
    int quad = lane >> 4, n = lane & 15;
    int wm = wid & 1, wn = wid >> 1;
    if (z < 2) {
        bf16* dst = (z == 0) ? qd : kd;
        for (int mi = 0; mi < 4; mi++)
            for (int ni = 0; ni < 4; ni++)
                for (int r = 0; r < 4; r++) {
                    int i = bm + wm * 64 + mi * 16 + quad * 4 + r;
                    int j = bn + wn * 64 + ni * 16 + n;
                    float val = acc[mi][ni][r] + bias[j];
                    if (z == 0) val *= QSCALE;
                    int b = i >> 11, srow = i & (S - 1);
                    int nh = j >> 6, d = j & (DH - 1);
                    dst[(((size_t)(b * NH + nh)) * S + srow) * DH + d] = (bf16)val;
                }
    } else {
        __syncthreads();                 // all waves done reading As/Bs
        bf16* T = smem;                  // [128 j][136] transposed tile
        for (int mi = 0; mi < 4; mi++)
            for (int ni = 0; ni < 4; ni++)
                for (int r = 0; r < 4; r++) {
                    int il = wm * 64 + mi * 16 + quad * 4 + r;
                    int jl = wn * 64 + ni * 16 + n;
                    float val = acc[mi][ni][r] + bias[bn + jl];
                    T[jl * 136 + il] = (bf16)val;
                }
        __syncthreads();
        int b = bm >> 11, srow0 = bm & (S - 1);
        int c16 = t & 15;                // 16B chunk within d-row
        #pragma unroll
        for (int p = 0; p < 8; p++) {
            int jl = (t >> 4) + p * 16;
            int j = bn + jl;
            int nh = j >> 6, d = j & (DH - 1);
            bf16x8 v = *(const bf16x8*)&T[jl * 136 + c16 * 8];
            *(bf16x8*)&vtd[(((size_t)(b * NH + nh)) * DH + d) * S
                           + srow0 + c16 * 8] = v;
        }
    }
}

// Output projection + bias + residual(h) -> tmp (bf16, row-major [M,H])
__global__ __launch_bounds__(256) void gemm_out(
    const bf16* __restrict__ ctx, const bf16* __restrict__ wo,
    const float* __restrict__ bo, const bf16* __restrict__ resid,
    bf16* __restrict__ dst) {
    __shared__ alignas(16) bf16 As[128 * 64];
    __shared__ alignas(16) bf16 Bs[128 * 64];
    int bm = blockIdx.x * 128, bn = blockIdx.y * 128;
    f32x4 acc[4][4];
    for (int mi = 0; mi < 4; mi++)
        for (int ni = 0; ni < 4; ni++)
            for (int r = 0; r < 4; r++) acc[mi][ni][r] = 0.0f;
    gemm128_mainloop(ctx, wo, bm, bn, As, Bs, acc);
    int lane = threadIdx.x & 63, wid = threadIdx.x >> 6;
    int quad = lane >> 4, n = lane & 15;
    int wm = wid & 1, wn = wid >> 1;
    for (int mi = 0; mi < 4; mi++)
        for (int ni = 0; ni < 4; ni++)
            for (int r = 0; r < 4; r++) {
                int i = bm + wm * 64 + mi * 16 + quad * 4 + r;
                int j = bn + wn * 64 + ni * 16 + n;
                float val = acc[mi][ni][r] + bo[j]
                          + (float)resid[(size_t)i * H + j];
                dst[(size_t)i * H + j] = (bf16)val;
            }
}

// ---------------------------------------------------------------------------
// Flash attention v9: key-split waves. 512 thr = 8 waves = 4 q-groups x
// 2 key-halves; each wave computes 32 q-rows x 64 keys per KV tile.
// O,l are pure sums over keys (exp2 softmax, no running max) so key-half
// partials combine once in the epilogue via LDS.
// LDS: Ks 16KB + Vs 16KB + Ps 8x4.5KB = 68KB -> 2 blocks/CU.
// ---------------------------------------------------------------------------
constexpr int LDP9 = 72;    // P row stride (64 + 8 pad)

#if __has_builtin(__builtin_amdgcn_exp2f)
#define EXP2(x) __builtin_amdgcn_exp2f(x)
#else
#define EXP2(x) exp2f(x)
#endif

__global__ __launch_bounds__(512, 4) void attn_kernel(
    const bf16* __restrict__ q, const bf16* __restrict__ k,
    const bf16* __restrict__ vt, const float* __restrict__ mask2,
    bf16* __restrict__ ctx) {
    int bh = blockIdx.y;                 // b*NH + nh
    int b = bh >> 3, nh = bh & 7;
    int t = threadIdx.x, wid = t >> 6, lane = t & 63;
    int quad = lane >> 4, n = lane & 15;
    int qg = wid >> 1, kh = wid & 1;     // q-group, key-half
    int qbase = blockIdx.x * 128 + qg * 32;
    int kO = kh * 64;                    // this wave's key offset in tile

    const bf16* Qp = q  + (size_t)bh * S * DH;
    const bf16* Kp = k  + (size_t)bh * S * DH;
    const bf16* Vt = vt + (size_t)bh * DH * S;
    const float* mrow = mask2 + (size_t)b * S;   // pre-scaled by log2e

    __shared__ alignas(16) bf16 smem[34816];     // 68KB
    bf16* Ks = smem;                     // [128 keys][64 d], swizzled
    bf16* Vs = smem + 8192;              // [64 d][128 keys], swizzled
    bf16* Pw = smem + 16384 + wid * (32 * LDP9); // per-wave P^T [q][key]

    int sw = (n & 7) * 8;                // frag-read xor

    bf16x8 qf[2][2];
    #pragma unroll
    for (int qt = 0; qt < 2; qt++)
        #pragma unroll
        for (int hh = 0; hh < 2; hh++)
            qf[qt][hh] = *(const bf16x8*)
                &Qp[(size_t)(qbase + qt * 16 + n) * DH + hh * 32 + quad * 8];

    f32x4 O[2][4];
    #pragma unroll
    for (int qt = 0; qt < 2; qt++)
        for (int i = 0; i < 4; i++)
            for (int r = 0; r < 4; r++) O[qt][i][r] = 0.0f;
    float l_run[2] = {0.0f, 0.0f};

    for (int kb = 0; kb < S; kb += 128) {
        __syncthreads();                 // prior tile's readers done
        #pragma unroll
        for (int i = 0; i < 2; i++) {    // stage K 128x64 + V^T 64x128
            int c = t + i * 512;
            {   // K: row=key (64 elems/row), unit=16B
                int row = c >> 3, part = c & 7;
                int csrc = (part * 8) ^ ((row & 7) * 8);
                __builtin_amdgcn_global_load_lds(
                    (g_void*)&Kp[(size_t)(kb + row) * DH + csrc],
                    (l_void*)&Ks[c * 8], 16, 0, 0);
            }
            {   // V^T: row=d (128 elems/row), unit=16B
                int row = c >> 4, part = c & 15;
                int csrc = (part * 8) ^ ((row & 7) * 8);
                __builtin_amdgcn_global_load_lds(
                    (g_void*)&Vt[(size_t)row * S + kb + csrc],
                    (l_void*)&Vs[c * 8], 16, 0, 0);
            }
        }
        __syncthreads();                 // drains vmcnt(0): tiles landed

        #pragma unroll
        for (int kt = 0; kt < 4; kt++) { // this wave's 64-key half
            const bf16* kr = &Ks[(kO + kt * 16 + n) * 64];
            bf16x8 ka = *(const bf16x8*)&kr[(quad * 8) ^ sw];
            bf16x8 kc = *(const bf16x8*)&kr[(32 + quad * 8) ^ sw];
            float4 mk = *(const float4*)&mrow[kb + kO + kt * 16 + quad * 4];
            #pragma unroll
            for (int qt = 0; qt < 2; qt++) {
                f32x4 s;
                for (int r = 0; r < 4; r++) s[r] = 0.0f;
                s = __builtin_amdgcn_mfma_f32_16x16x32_bf16(ka, qf[qt][0], s, 0, 0, 0);
                s = __builtin_amdgcn_mfma_f32_16x16x32_bf16(kc, qf[qt][1], s, 0, 0, 0);
                float p0 = EXP2(s[0] + mk.x);
                float p1 = EXP2(s[1] + mk.y);
                float p2 = EXP2(s[2] + mk.z);
                float p3 = EXP2(s[3] + mk.w);
                l_run[qt] += (p0 + p1) + (p2 + p3);
                bf16x4 w;
                w[0] = (bf16)p0; w[1] = (bf16)p1; w[2] = (bf16)p2; w[3] = (bf16)p3;
                *(bf16x4*)&Pw[(qt * 16 + n) * LDP9 + kt * 16 + quad * 4] = w;
            }
        }

        __builtin_amdgcn_s_setprio(1);
        #pragma unroll
        for (int ks = 0; ks < 2; ks++)
            #pragma unroll
            for (int qt = 0; qt < 2; qt++) {
                bf16x8 pf = *(const bf16x8*)
                    &Pw[(qt * 16 + n) * LDP9 + ks * 32 + quad * 8];
                #pragma unroll
                for (int dt = 0; dt < 4; dt++) {
                    bf16x8 vf = *(const bf16x8*)
                        &Vs[(dt * 16 + n) * 128 + ((kO + ks * 32 + quad * 8) ^ sw)];
                    O[qt][dt] = __builtin_amdgcn_mfma_f32_16x16x32_bf16(
                        vf, pf, O[qt][dt], 0, 0, 0);
                }
            }
        __builtin_amdgcn_s_setprio(0);
    }

    // --- combine key-half partials (O,l are pure sums) -------------------
    float* Ob = (float*)smem;            // [4 qg][32 q][68] fp32 (2-way banks)
    float* Lb = Ob + 4 * 32 * 68;        // [4 qg][2 qt][64 lanes]
    __syncthreads();                     // all compute done; smem reusable
    if (kh) {
        #pragma unroll
        for (int qt = 0; qt < 2; qt++) {
            #pragma unroll
            for (int dt = 0; dt < 4; dt++)
                *(f32x4*)&Ob[(qg * 32 + qt * 16 + n) * 68 + dt * 16 + quad * 4]
                    = O[qt][dt];
            Lb[(qg * 2 + qt) * 64 + lane] = l_run[qt];
        }
    }
    __syncthreads();
    if (!kh) {
        #pragma unroll
        for (int qt = 0; qt < 2; qt++) {
            float l = l_run[qt] + Lb[(qg * 2 + qt) * 64 + lane];
            l += __shfl_xor(l, 16, 64);
            l += __shfl_xor(l, 32, 64);
            float linv = 1.0f / l;
            int srow = qbase + qt * 16 + n;
            #pragma unroll
            for (int dt = 0; dt < 4; dt++) {
                f32x4 po = *(const f32x4*)
                    &Ob[(qg * 32 + qt * 16 + n) * 68 + dt * 16 + quad * 4];
                bf16x4 o4;
                for (int r = 0; r < 4; r++)
                    o4[r] = (bf16)((O[qt][dt][r] + po[r]) * linv);
                int col = nh * 64 + dt * 16 + quad * 4;
                *(bf16x4*)&ctx[((size_t)(b * S + srow)) * H + col] = o4;
            }
        }
    }
}

// ---------------------------------------------------------------------------
extern "C" void kernel_launch(void* const* d_in, const int* in_sizes, int n_in,
                              void* d_out, int out_size, void* d_ws, size_t ws_size,
                              hipStream_t stream) {
    const float* hidden = (const float*)d_in[0];
    const float* mask   = (const float*)d_in[1];
    const float* ln1_g  = (const float*)d_in[2];
    const float* ln1_b  = (const float*)d_in[3];
    const float* wq = (const float*)d_in[4],  *bq = (const float*)d_in[5];
    const float* wk = (const float*)d_in[6],  *bk = (const float*)d_in[7];
    const float* wv = (const float*)d_in[8],  *bv = (const float*)d_in[9];
    const float* wo = (const float*)d_in[10], *bo = (const float*)d_in[11];
    const float* ln2_g = (const float*)d_in[12];
    const float* ln2_b = (const float*)d_in[13];

    const size_t T = (size_t)M * H;     // 4M elems per activation tensor
    bf16* wb  = (bf16*)d_ws;            // 4 weights, bf16: 4*WELEM
    bf16* h   = wb  + (size_t)4 * WELEM;
    bf16* qd  = h   + T;
    bf16* kd  = qd  + T;
    bf16* vtd = kd  + T;
    bf16* ctx = vtd + T;
    float* mask2 = (float*)(ctx + T);   // B*S fp32, mask*log2e
    bf16* tmp = qd;                     // qd is dead after attn_kernel

    prep<<<M + 1024 + 32, 256, 0, stream>>>(
        hidden, ln1_g, ln1_b, wq, wk, wv, wo, mask, h, wb, mask2);
    gemm_qkv<<<dim3(M / 128, H / 128, 3), 256, 0, stream>>>(
        h, wb, bq, bk, bv, qd, kd, vtd);
    attn_kernel<<<dim3(S / 128, Bsz * NH), 512, 0, stream>>>(qd, kd, vtd, mask2, ctx);
    gemm_out<<<dim3(M / 128, H / 128), 256, 0, stream>>>(
        ctx, wb + (size_t)3 * WELEM, bo, h, tmp);
    ln_bf16_f32<<<M, 256, 0, stream>>>(tmp, ln2_g, ln2_b, (float*)d_out);
}

// Round 7
// 178.400 us; speedup vs baseline: 1.7039x; 1.0816x over previous
//
#include <hip/hip_runtime.h>

typedef __bf16 bf16;
typedef __bf16 bf16x2 __attribute__((ext_vector_type(2)));
typedef __bf16 bf16x4 __attribute__((ext_vector_type(4)));
typedef __bf16 bf16x8 __attribute__((ext_vector_type(8)));
typedef float f32x4 __attribute__((ext_vector_type(4)));

typedef __attribute__((address_space(1))) const void g_void;
typedef __attribute__((address_space(3))) void l_void;

constexpr int Bsz = 4, S = 2048, H = 512, NH = 8, DH = 64;
constexpr int M = Bsz * S;   // 8192 rows
constexpr int K = H;         // 512 reduction dim
constexpr int WELEM = H * H; // 262144 elems per weight matrix
constexpr float LOG2E  = 1.44269504f;
constexpr float QSCALE = 0.125f * LOG2E;  // fold 1/sqrt(DH)*log2e into q

// ---------------------------------------------------------------------------
// prep: fused convert_w (4 weights fp32->bf16) + scale_mask + ln1.
// ---------------------------------------------------------------------------
__global__ __launch_bounds__(256) void prep(
    const float* __restrict__ hidden, const float* __restrict__ ln1_g,
    const float* __restrict__ ln1_b,
    const float* __restrict__ w0, const float* __restrict__ w1,
    const float* __restrict__ w2, const float* __restrict__ w3,
    const float* __restrict__ mask,
    bf16* __restrict__ h, bf16* __restrict__ wb, float* __restrict__ mask2) {
    int bx = blockIdx.x;
    int t = threadIdx.x;
    if (bx < M) {                        // ---- ln1: fp32 -> bf16, row = bx
        int row = bx;
        float2 xv = *(const float2*)(hidden + (size_t)row * H + t * 2);
        float v0 = xv.x, v1 = xv.y;
        float s = v0 + v1, s2 = v0 * v0 + v1 * v1;
        for (int off = 1; off < 64; off <<= 1) {
            s  += __shfl_xor(s,  off, 64);
            s2 += __shfl_xor(s2, off, 64);
        }
        __shared__ float red[8];
        int wid = t >> 6;
        if ((t & 63) == 0) { red[wid * 2] = s; red[wid * 2 + 1] = s2; }
        __syncthreads();
        s  = red[0] + red[2] + red[4] + red[6];
        s2 = red[1] + red[3] + red[5] + red[7];
        float mu  = s * (1.0f / H);
        float var = s2 * (1.0f / H) - mu * mu;
        float inv = rsqrtf(var + 1e-12f);
        float2 gv = *(const float2*)(ln1_g + t * 2);
        float2 bv = *(const float2*)(ln1_b + t * 2);
        bf16x2 out;
        out.x = (bf16)((v0 - mu) * inv * gv.x + bv.x);
        out.y = (bf16)((v1 - mu) * inv * gv.y + bv.y);
        *(bf16x2*)(h + (size_t)row * H + t * 2) = out;
    } else if (bx < M + 1024) {          // ---- convert_w
        int idx = bx - M;
        int y = idx >> 8, xx = idx & 255;
        const float* src = (y == 0) ? w0 : (y == 1) ? w1 : (y == 2) ? w2 : w3;
        bf16* d = wb + (size_t)y * WELEM;
        int i = (xx * 256 + t) * 4;
        float4 v = *(const float4*)(src + i);
        bf16x4 o;
        o.x = (bf16)v.x; o.y = (bf16)v.y; o.z = (bf16)v.z; o.w = (bf16)v.w;
        *(bf16x4*)(d + i) = o;
    } else {                             // ---- scale_mask
        int i = (bx - M - 1024) * 256 + t;
        mask2[i] = mask[i] * LOG2E;
    }
}

// LN2: bf16 in -> fp32 out.
__global__ __launch_bounds__(256) void ln_bf16_f32(
    const bf16* __restrict__ x, const float* __restrict__ g,
    const float* __restrict__ b, float* __restrict__ y) {
    int row = blockIdx.x;
    int t = threadIdx.x;
    bf16x2 xv = *(const bf16x2*)(x + (size_t)row * H + t * 2);
    float v0 = (float)xv.x, v1 = (float)xv.y;
    float s = v0 + v1, s2 = v0 * v0 + v1 * v1;
    for (int off = 1; off < 64; off <<= 1) {
        s  += __shfl_xor(s,  off, 64);
        s2 += __shfl_xor(s2, off, 64);
    }
    __shared__ float red[8];
    int wid = t >> 6;
    if ((t & 63) == 0) { red[wid * 2] = s; red[wid * 2 + 1] = s2; }
    __syncthreads();
    s  = red[0] + red[2] + red[4] + red[6];
    s2 = red[1] + red[3] + red[5] + red[7];
    float mu  = s * (1.0f / H);
    float var = s2 * (1.0f / H) - mu * mu;
    float inv = rsqrtf(var + 1e-12f);
    float2 gv = *(const float2*)(g + t * 2);
    float2 bv = *(const float2*)(b + t * 2);
    float2 out;
    out.x = (v0 - mu) * inv * gv.x + bv.x;
    out.y = (v1 - mu) * inv * gv.y + bv.y;
    *(float2*)(y + (size_t)row * H + t * 2) = out;
}

// ---------------------------------------------------------------------------
// 512-thread GEMM mainloop: C[BM x BN] tile of A[M,K]@W[N,K]^T.
// 8 waves (2 wm x 4 wn), per-wave (BM/2)x(BN/4) = MI x NI 16x16 frags.
// Same 2-barrier / BK=64 / global_load_lds / XOR-swizzle structure as the
// proven 256-thr version; doubling waves per block raises waves/CU
// (v8 attn lesson: conserve per-block tile+staging, add concurrency).
// ---------------------------------------------------------------------------
template<int BM, int BN, int MI, int NI>
__device__ inline void gemm_mainloop512(const bf16* __restrict__ A,
                                        const bf16* __restrict__ W,
                                        int bm, int bn,
                                        bf16* As, bf16* Bs, f32x4 acc[MI][NI]) {
    int t = threadIdx.x;
    int lane = t & 63, wid = t >> 6;     // 8 waves
    int quad = lane >> 4, n = lane & 15;
    int wm = wid & 1, wn = wid >> 1;     // 2 x 4 wave grid
    int sw = (n & 7) * 8;                // frag-read xor (row&7)*8, row%8==n%8
    int srow = lane >> 3;                // staging: row within 8-row chunk
    int scol = (lane & 7) * 8;           // staging: col base (elems)
    constexpr int APW = BM / 64;         // A 8-row chunks per wave
    constexpr int BPW = BN / 64;
    constexpr int RM = MI * 16;          // rows per wm step
    constexpr int RN = NI * 16;          // cols per wn step
    for (int kt = 0; kt < K; kt += 64) {
        __syncthreads();                 // prior tile's readers done
        #pragma unroll
        for (int i = 0; i < APW; i++) {
            int chunk = wid * APW + i;   // wave-uniform
            int row = chunk * 8 + srow;
            int csrc = scol ^ ((row & 7) * 8);
            __builtin_amdgcn_global_load_lds(
                (g_void*)&A[(size_t)(bm + row) * K + kt + csrc],
                (l_void*)&As[chunk * 512], 16, 0, 0);
        }
        #pragma unroll
        for (int i = 0; i < BPW; i++) {
            int chunk = wid * BPW + i;
            int row = chunk * 8 + srow;
            int csrc = scol ^ ((row & 7) * 8);
            __builtin_amdgcn_global_load_lds(
                (g_void*)&W[(size_t)(bn + row) * K + kt + csrc],
                (l_void*)&Bs[chunk * 512], 16, 0, 0);
        }
        __syncthreads();                 // drains vmcnt(0) before compute
        #pragma unroll
        for (int half = 0; half < 2; half++) {
            bf16x8 af[MI], bfr[NI];
            int c = (half * 32 + quad * 8) ^ sw;
            #pragma unroll
            for (int mi = 0; mi < MI; mi++)
                af[mi] = *(const bf16x8*)&As[(wm * RM + mi * 16 + n) * 64 + c];
            #pragma unroll
            for (int ni = 0; ni < NI; ni++)
                bfr[ni] = *(const bf16x8*)&Bs[(wn * RN + ni * 16 + n) * 64 + c];
            #pragma unroll
            for (int mi = 0; mi < MI; mi++)
                #pragma unroll
                for (int ni = 0; ni < NI; ni++)
                    acc[mi][ni] = __builtin_amdgcn_mfma_f32_16x16x32_bf16(
                        af[mi], bfr[ni], acc[mi][ni], 0, 0, 0);
        }
    }
}

// QKV projection. grid = (M/128, H/128, 3), 512 thr; z=0:q (QSCALE),
// z=1:k ([B,NH,S,DH]), z=2: v transposed [B,NH,DH,S] via LDS transpose.
__global__ __launch_bounds__(512, 4) void gemm_qkv(
    const bf16* __restrict__ h, const bf16* __restrict__ wb,
    const float* __restrict__ bq, const float* __restrict__ bk,
    const float* __restrict__ bv,
    bf16* __restrict__ qd, bf16* __restrict__ kd, bf16* __restrict__ vtd) {
    __shared__ alignas(16) bf16 smem[17408];   // 34.8KB: As+Bs | T[128][136]
    bf16* As = smem;
    bf16* Bs = smem + 8192;
    int bm = blockIdx.x * 128, bn = blockIdx.y * 128, z = blockIdx.z;
    const bf16* W = wb + (size_t)z * WELEM;
    const float* bias = (z == 0) ? bq : (z == 1) ? bk : bv;
    f32x4 acc[4][2];
    for (int mi = 0; mi < 4; mi++)
        for (int ni = 0; ni < 2; ni++)
            for (int r = 0; r < 4; r++) acc[mi][ni][r] = 0.0f;
    gemm_mainloop512<128, 128, 4, 2>(h, W, bm, bn, As, Bs, acc);
    int t = threadIdx.x;
    int lane = t & 63, wid = t >> 6;
    int quad = lane >> 4, n = lane & 15;
    int wm = wid & 1, wn = wid >> 1;
    if (z < 2) {
        bf16* dst = (z == 0) ? qd : kd;
        for (int mi = 0; mi < 4; mi++)
            for (int ni = 0; ni < 2; ni++)
                for (int r = 0; r < 4; r++) {
                    int i = bm + wm * 64 + mi * 16 + quad * 4 + r;
                    int j = bn + wn * 32 + ni * 16 + n;
                    float val = acc[mi][ni][r] + bias[j];
                    if (z == 0) val *= QSCALE;
                    int b = i >> 11, srow = i & (S - 1);
                    int nh = j >> 6, d = j & (DH - 1);
                    dst[(((size_t)(b * NH + nh)) * S + srow) * DH + d] = (bf16)val;
                }
    } else {
        __syncthreads();                 // all waves done reading As/Bs
        bf16* T = smem;                  // [128 j][136] transposed tile
        for (int mi = 0; mi < 4; mi++)
            for (int ni = 0; ni < 2; ni++)
                for (int r = 0; r < 4; r++) {
                    int il = wm * 64 + mi * 16 + quad * 4 + r;
                    int jl = wn * 32 + ni * 16 + n;
                    float val = acc[mi][ni][r] + bias[bn + jl];
                    T[jl * 136 + il] = (bf16)val;
                }
        __syncthreads();
        int b = bm >> 11, srow0 = bm & (S - 1);
        int c16 = t & 15;                // 16B chunk within d-row
        #pragma unroll
        for (int p = 0; p < 4; p++) {
            int jl = (t >> 4) + p * 32;
            int j = bn + jl;
            int nh = j >> 6, d = j & (DH - 1);
            bf16x8 v = *(const bf16x8*)&T[jl * 136 + c16 * 8];
            *(bf16x8*)&vtd[(((size_t)(b * NH + nh)) * DH + d) * S
                           + srow0 + c16 * 8] = v;
        }
    }
}

// Output projection + bias + residual(h) -> tmp (bf16, row-major [M,H]).
// BM=64 x BN=128 tiles, 512 thr: grid (128,4)=512 blocks -> 2 blocks/CU x
// 8 waves = 16 waves/CU (prev: 256 blocks x 4 waves = 1 wave/SIMD,
// latency-naked). Per-wave 32x32 (MI=NI=2). LDS 24KB.
__global__ __launch_bounds__(512, 4) void gemm_out(
    const bf16* __restrict__ ctx, const bf16* __restrict__ wo,
    const float* __restrict__ bo, const bf16* __restrict__ resid,
    bf16* __restrict__ dst) {
    __shared__ alignas(16) bf16 As[64 * 64];
    __shared__ alignas(16) bf16 Bs[128 * 64];
    int bm = blockIdx.x * 64, bn = blockIdx.y * 128;
    f32x4 acc[2][2];
    for (int mi = 0; mi < 2; mi++)
        for (int ni = 0; ni < 2; ni++)
            for (int r = 0; r < 4; r++) acc[mi][ni][r] = 0.0f;
    gemm_mainloop512<64, 128, 2, 2>(ctx, wo, bm, bn, As, Bs, acc);
    int lane = threadIdx.x & 63, wid = threadIdx.x >> 6;
    int quad = lane >> 4, n = lane & 15;
    int wm = wid & 1, wn = wid >> 1;
    for (int mi = 0; mi < 2; mi++)
        for (int ni = 0; ni < 2; ni++)
            for (int r = 0; r < 4; r++) {
                int i = bm + wm * 32 + mi * 16 + quad * 4 + r;
                int j = bn + wn * 32 + ni * 16 + n;
                float val = acc[mi][ni][r] + bo[j]
                          + (float)resid[(size_t)i * H + j];
                dst[(size_t)i * H + j] = (bf16)val;
            }
}

// ---------------------------------------------------------------------------
// Flash attention v9: key-split waves. 512 thr = 8 waves = 4 q-groups x
// 2 key-halves; each wave computes 32 q-rows x 64 keys per KV tile.
// O,l are pure sums over keys (exp2 softmax, no running max) so key-half
// partials combine once in the epilogue via LDS.
// LDS: Ks 16KB + Vs 16KB + Ps 8x4.5KB = 68KB -> 2 blocks/CU.
// ---------------------------------------------------------------------------
constexpr int LDP9 = 72;    // P row stride (64 + 8 pad)

#if __has_builtin(__builtin_amdgcn_exp2f)
#define EXP2(x) __builtin_amdgcn_exp2f(x)
#else
#define EXP2(x) exp2f(x)
#endif

__global__ __launch_bounds__(512, 4) void attn_kernel(
    const bf16* __restrict__ q, const bf16* __restrict__ k,
    const bf16* __restrict__ vt, const float* __restrict__ mask2,
    bf16* __restrict__ ctx) {
    int bh = blockIdx.y;                 // b*NH + nh
    int b = bh >> 3, nh = bh & 7;
    int t = threadIdx.x, wid = t >> 6, lane = t & 63;
    int quad = lane >> 4, n = lane & 15;
    int qg = wid >> 1, kh = wid & 1;     // q-group, key-half
    int qbase = blockIdx.x * 128 + qg * 32;
    int kO = kh * 64;                    // this wave's key offset in tile

    const bf16* Qp = q  + (size_t)bh * S * DH;
    const bf16* Kp = k  + (size_t)bh * S * DH;
    const bf16* Vt = vt + (size_t)bh * DH * S;
    const float* mrow = mask2 + (size_t)b * S;   // pre-scaled by log2e

    __shared__ alignas(16) bf16 smem[34816];     // 68KB
    bf16* Ks = smem;                     // [128 keys][64 d], swizzled
    bf16* Vs = smem + 8192;              // [64 d][128 keys], swizzled
    bf16* Pw = smem + 16384 + wid * (32 * LDP9); // per-wave P^T [q][key]

    int sw = (n & 7) * 8;                // frag-read xor

    bf16x8 qf[2][2];
    #pragma unroll
    for (int qt = 0; qt < 2; qt++)
        #pragma unroll
        for (int hh = 0; hh < 2; hh++)
            qf[qt][hh] = *(const bf16x8*)
                &Qp[(size_t)(qbase + qt * 16 + n) * DH + hh * 32 + quad * 8];

    f32x4 O[2][4];
    #pragma unroll
    for (int qt = 0; qt < 2; qt++)
        for (int i = 0; i < 4; i++)
            for (int r = 0; r < 4; r++) O[qt][i][r] = 0.0f;
    float l_run[2] = {0.0f, 0.0f};

    for (int kb = 0; kb < S; kb += 128) {
        __syncthreads();                 // prior tile's readers done
        #pragma unroll
        for (int i = 0; i < 2; i++) {    // stage K 128x64 + V^T 64x128
            int c = t + i * 512;
            {   // K: row=key (64 elems/row), unit=16B
                int row = c >> 3, part = c & 7;
                int csrc = (part * 8) ^ ((row & 7) * 8);
                __builtin_amdgcn_global_load_lds(
                    (g_void*)&Kp[(size_t)(kb + row) * DH + csrc],
                    (l_void*)&Ks[c * 8], 16, 0, 0);
            }
            {   // V^T: row=d (128 elems/row), unit=16B
                int row = c >> 4, part = c & 15;
                int csrc = (part * 8) ^ ((row & 7) * 8);
                __builtin_amdgcn_global_load_lds(
                    (g_void*)&Vt[(size_t)row * S + kb + csrc],
                    (l_void*)&Vs[c * 8], 16, 0, 0);
            }
        }
        __syncthreads();                 // drains vmcnt(0): tiles landed

        #pragma unroll
        for (int kt = 0; kt < 4; kt++) { // this wave's 64-key half
            const bf16* kr = &Ks[(kO + kt * 16 + n) * 64];
            bf16x8 ka = *(const bf16x8*)&kr[(quad * 8) ^ sw];
            bf16x8 kc = *(const bf16x8*)&kr[(32 + quad * 8) ^ sw];
            float4 mk = *(const float4*)&mrow[kb + kO + kt * 16 + quad * 4];
            #pragma unroll
            for (int qt = 0; qt < 2; qt++) {
                f32x4 s;
                for (int r = 0; r < 4; r++) s[r] = 0.0f;
                s = __builtin_amdgcn_mfma_f32_16x16x32_bf16(ka, qf[qt][0], s, 0, 0, 0);
                s = __builtin_amdgcn_mfma_f32_16x16x32_bf16(kc, qf[qt][1], s, 0, 0, 0);
                float p0 = EXP2(s[0] + mk.x);
                float p1 = EXP2(s[1] + mk.y);
                float p2 = EXP2(s[2] + mk.z);
                float p3 = EXP2(s[3] + mk.w);
                l_run[qt] += (p0 + p1) + (p2 + p3);
                bf16x4 w;
                w[0] = (bf16)p0; w[1] = (bf16)p1; w[2] = (bf16)p2; w[3] = (bf16)p3;
                *(bf16x4*)&Pw[(qt * 16 + n) * LDP9 + kt * 16 + quad * 4] = w;
            }
        }

        __builtin_amdgcn_s_setprio(1);
        #pragma unroll
        for (int ks = 0; ks < 2; ks++)
            #pragma unroll
            for (int qt = 0; qt < 2; qt++) {
                bf16x8 pf = *(const bf16x8*)
                    &Pw[(qt * 16 + n) * LDP9 + ks * 32 + quad * 8];
                #pragma unroll
                for (int dt = 0; dt < 4; dt++) {
                    bf16x8 vf = *(const bf16x8*)
                        &Vs[(dt * 16 + n) * 128 + ((kO + ks * 32 + quad * 8) ^ sw)];
                    O[qt][dt] = __builtin_amdgcn_mfma_f32_16x16x32_bf16(
                        vf, pf, O[qt][dt], 0, 0, 0);
                }
            }
        __builtin_amdgcn_s_setprio(0);
    }

    // --- combine key-half partials (O,l are pure sums) -------------------
    float* Ob = (float*)smem;            // [4 qg][32 q][68] fp32 (2-way banks)
    float* Lb = Ob + 4 * 32 * 68;        // [4 qg][2 qt][64 lanes]
    __syncthreads();                     // all compute done; smem reusable
    if (kh) {
        #pragma unroll
        for (int qt = 0; qt < 2; qt++) {
            #pragma unroll
            for (int dt = 0; dt < 4; dt++)
                *(f32x4*)&Ob[(qg * 32 + qt * 16 + n) * 68 + dt * 16 + quad * 4]
                    = O[qt][dt];
            Lb[(qg * 2 + qt) * 64 + lane] = l_run[qt];
        }
    }
    __syncthreads();
    if (!kh) {
        #pragma unroll
        for (int qt = 0; qt < 2; qt++) {
            float l = l_run[qt] + Lb[(qg * 2 + qt) * 64 + lane];
            l += __shfl_xor(l, 16, 64);
            l += __shfl_xor(l, 32, 64);
            float linv = 1.0f / l;
            int srow = qbase + qt * 16 + n;
            #pragma unroll
            for (int dt = 0; dt < 4; dt++) {
                f32x4 po = *(const f32x4*)
                    &Ob[(qg * 32 + qt * 16 + n) * 68 + dt * 16 + quad * 4];
                bf16x4 o4;
                for (int r = 0; r < 4; r++)
                    o4[r] = (bf16)((O[qt][dt][r] + po[r]) * linv);
                int col = nh * 64 + dt * 16 + quad * 4;
                *(bf16x4*)&ctx[((size_t)(b * S + srow)) * H + col] = o4;
            }
        }
    }
}

// ---------------------------------------------------------------------------
extern "C" void kernel_launch(void* const* d_in, const int* in_sizes, int n_in,
                              void* d_out, int out_size, void* d_ws, size_t ws_size,
                              hipStream_t stream) {
    const float* hidden = (const float*)d_in[0];
    const float* mask   = (const float*)d_in[1];
    const float* ln1_g  = (const float*)d_in[2];
    const float* ln1_b  = (const float*)d_in[3];
    const float* wq = (const float*)d_in[4],  *bq = (const float*)d_in[5];
    const float* wk = (const float*)d_in[6],  *bk = (const float*)d_in[7];
    const float* wv = (const float*)d_in[8],  *bv = (const float*)d_in[9];
    const float* wo = (const float*)d_in[10], *bo = (const float*)d_in[11];
    const float* ln2_g = (const float*)d_in[12];
    const float* ln2_b = (const float*)d_in[13];

    const size_t T = (size_t)M * H;     // 4M elems per activation tensor
    bf16* wb  = (bf16*)d_ws;            // 4 weights, bf16: 4*WELEM
    bf16* h   = wb  + (size_t)4 * WELEM;
    bf16* qd  = h   + T;
    bf16* kd  = qd  + T;
    bf16* vtd = kd  + T;
    bf16* ctx = vtd + T;
    float* mask2 = (float*)(ctx + T);   // B*S fp32, mask*log2e
    bf16* tmp = qd;                     // qd is dead after attn_kernel

    prep<<<M + 1024 + 32, 256, 0, stream>>>(
        hidden, ln1_g, ln1_b, wq, wk, wv, wo, mask, h, wb, mask2);
    gemm_qkv<<<dim3(M / 128, H / 128, 3), 512, 0, stream>>>(
        h, wb, bq, bk, bv, qd, kd, vtd);
    attn_kernel<<<dim3(S / 128, Bsz * NH), 512, 0, stream>>>(qd, kd, vtd, mask2, ctx);
    gemm_out<<<dim3(M / 64, H / 128), 512, 0, stream>>>(
        ctx, wb + (size_t)3 * WELEM, bo, h, tmp);
    ln_bf16_f32<<<M, 256, 0, stream>>>(tmp, ln2_g, ln2_b, (float*)d_out);
}